// Round 22
// baseline (553.474 us; speedup 1.0000x reference)
//
#include <hip/hip_runtime.h>
#include <hip/hip_bf16.h>
#include <math.h>

#define PP 40000
#define HDIM 200
#define WDIM 200
#define NEPS 1e-8f
#define GX 157                 // (PP+255)/256
#define NPART (GX*12)

// workspace layout (float offsets)
#define OFF_COM    0            // 15*PP
#define OFF_ENT    (15*PP)      // 15*PP
#define OFF_MASK   (30*PP)      // 12*PP
#define OFF_DEN    (42*PP)      // 12*PP (fallback path only)
#define OFF_LOGITS (54*PP)      // 15*PP
#define OFF_MISC   (69*PP)      // 64 floats
#define OFF_XTG_F  (69*PP + 64)             // Xtg bf16 [bt][8][PP][8]: 3*PP*64 shorts
#define OFF_XFT_F  (OFF_XTG_F + 3*PP*32)    // Xft bf16 [im12][8][PP][8]: 12*PP*64 shorts; z fp32 (135*PP) overlaps (dead before Xft written)
#define OFF_WBF_F  (OFF_XFT_F + 12*PP*32)   // wbf bf16 FRAGMENT-ORDERED: w1 16384 + w2 4096 shorts
#define OFF_CNT_F  (OFF_WBF_F + 10240)      // partial mask counts: NPART uints
#define WS_NEED ((size_t)(OFF_CNT_F + NPART + 64)*4)

typedef __attribute__((ext_vector_type(8))) short bf16x8;
typedef __attribute__((ext_vector_type(4))) float f32x4;

__device__ __forceinline__ short f2bf(float f){
    __hip_bfloat16 h = __float2bfloat16(f);   // RTNE
    return *reinterpret_cast<short*>(&h);
}
__device__ __forceinline__ float bf2f(short s){
    return __uint_as_float(((unsigned)(unsigned short)s) << 16);
}

__device__ __forceinline__ unsigned f2ord(float f){
    unsigned u = __float_as_uint(f);
    return (u & 0x80000000u) ? ~u : (u | 0x80000000u);
}
__device__ __forceinline__ float ord2f(unsigned u){
    unsigned v = (u & 0x80000000u) ? (u & 0x7fffffffu) : ~u;
    return __uint_as_float(v);
}

// Clamped tap offsets (per-pixel scalar form, used by small kernels)
__device__ __forceinline__ void tap_setup(int p, int* off, bool* val){
    int h = p / WDIM, w = p - h*WDIM;
#pragma unroll
    for (int ky=0;ky<3;ky++)
#pragma unroll
        for (int kx=0;kx<3;kx++){
            int t = ky*3+kx;
            int hh = h+ky-1, ww = w+kx-1;
            val[t] = (hh>=0)&&(hh<HDIM)&&(ww>=0)&&(ww<WDIM);
            int hc = min(max(hh,0),HDIM-1);
            int wc = min(max(ww,0),WDIM-1);
            off[t] = hc*WDIM+wc;
        }
}

__global__ void k_init(unsigned* misc){
    int t = threadIdx.x;
    if (t < 12) misc[t] = 0xFFFFFFFFu;        // min (sortable) = +inf
    else if (t < 25) misc[t] = 0u;            // max = -inf, count = 0
}

// one-shot fp32 -> bf16 weight conversion into MFMA FRAGMENT ORDER:
// wbf[((nt*4+ks)*64 + lane)*8 + e], lane = kg*16+ln
__global__ __launch_bounds__(256) void k_wcvt(const float* __restrict__ w1,
        const float* __restrict__ w2, short* __restrict__ wbf)
{
    int i = blockIdx.x*256 + threadIdx.x;
    if (i < 16384){
        int e = i&7, l = (i>>3)&63, ks = (i>>9)&3, nt = i>>11;
        int ln = l&15, kg = l>>4;
        wbf[i] = f2bf(w1[(nt*16+ln)*128 + ks*32 + kg*8 + e]);
    } else if (i < 20480){
        int j = i - 16384;
        int e = j&7, l = (j>>3)&63, ks = (j>>9)&3, nt2 = j>>11;
        int ln = l&15, kg = l>>4;
        wbf[i] = f2bf(w2[(nt2*16+ln)*128 + ks*32 + kg*8 + e]);
    }
}

// ---------------------------------------------------------------------------
// conv pass 1 (4 px/thread, f32x4, unroll 4 -- r21 winner):
// z_t(q) = sum_c w[c,t]*x[c,q]; min/max fused. grid (40, 15), block 256.
// ---------------------------------------------------------------------------
__global__ __launch_bounds__(256) void k_csum(const float* __restrict__ bevs,
        const float* __restrict__ cw, unsigned* __restrict__ misc,
        float* __restrict__ z)
{
    int img = blockIdx.y;
    int n = img % 5;
    int idx = blockIdx.x*256 + threadIdx.x;
    bool act = idx < PP/4;
    int p = idx*4;
    float vmin = INFINITY, vmax = -INFINITY;
    f32x4 acc[9];
#pragma unroll
    for (int t=0;t<9;t++) acc[t] = (f32x4){0.f,0.f,0.f,0.f};
    if (act){
        const float* src = bevs + (size_t)img*64*PP;
#pragma unroll 4
        for (int c=0;c<64;c++){
            f32x4 v = *(const f32x4*)&src[(size_t)c*PP + p];
            vmin = fminf(fminf(fminf(vmin, v[0]), fminf(v[1], v[2])), v[3]);
            vmax = fmaxf(fmaxf(fmaxf(vmax, v[0]), fmaxf(v[1], v[2])), v[3]);
#pragma unroll
            for (int t=0;t<9;t++){
                float w = cw[c*9+t];
#pragma unroll
                for (int j=0;j<4;j++) acc[t][j] = fmaf(w, v[j], acc[t][j]);
            }
        }
        float* zimg = z + (size_t)img*9*PP;
#pragma unroll
        for (int t=0;t<9;t++)
            *(f32x4*)&zimg[(size_t)t*PP + p] = acc[t];
    }
    if (n > 0){
#pragma unroll
        for (int s=32;s>0;s>>=1){
            vmin = fminf(vmin, __shfl_xor(vmin, s, 64));
            vmax = fmaxf(vmax, __shfl_xor(vmax, s, 64));
        }
        if ((threadIdx.x & 63) == 0){
            int im12 = (img/5)*4 + (n-1);
            atomicMin(&misc[im12], f2ord(vmin));
            atomicMax(&misc[12+im12], f2ord(vmax));
        }
    }
}

// conv pass 2: com(p) = relu(cb + sum_t [val] z_t(p+delta_t))
__global__ __launch_bounds__(256) void k_cfin(const float* __restrict__ z,
        const float* __restrict__ cb, float* __restrict__ com)
{
    int img = blockIdx.y;
    int p = blockIdx.x*256 + threadIdx.x;
    if (p >= PP) return;
    int off[9]; bool val[9];
    tap_setup(p, off, val);
    const float* zimg = z + (size_t)img*9*PP;
    float v[9];
#pragma unroll
    for (int t=0;t<9;t++) v[t] = zimg[(size_t)t*PP + off[t]];
    float acc = cb[0];
#pragma unroll
    for (int t=0;t<9;t++) acc += val[t] ? v[t] : 0.0f;
    com[(size_t)img*PP + p] = fmaxf(acc, 0.0f);
}

// ---------------------------------------------------------------------------
// FALLBACK conv if ws too small
// ---------------------------------------------------------------------------
__global__ __launch_bounds__(256) void k_conv(const float* __restrict__ bevs,
        const float* __restrict__ cw, const float* __restrict__ cb,
        float* __restrict__ com, unsigned* __restrict__ misc)
{
    int img = blockIdx.y;
    int n = img % 5;
    int p = blockIdx.x*256 + threadIdx.x;
    float vmin = INFINITY, vmax = -INFINITY;
    if (p < PP){
        int off[9]; bool val[9];
        tap_setup(p, off, val);
        const float* src = bevs + (size_t)img*64*PP;
        float acc = cb[0];
#pragma unroll 2
        for (int c=0;c<64;c++){
            const float* sc = src + (size_t)c*PP;
            float v[9];
#pragma unroll
            for (int t=0;t<9;t++) v[t] = sc[off[t]];
            vmin = fminf(vmin, v[4]); vmax = fmaxf(vmax, v[4]);
#pragma unroll
            for (int t=0;t<9;t++)
                acc = fmaf(cw[c*9+t], val[t] ? v[t] : 0.0f, acc);
        }
        com[(size_t)img*PP + p] = fmaxf(acc, 0.0f);
    }
    if (n > 0){
#pragma unroll
        for (int s=32;s>0;s>>=1){
            vmin = fminf(vmin, __shfl_xor(vmin, s, 64));
            vmax = fmaxf(vmax, __shfl_xor(vmax, s, 64));
        }
        if ((threadIdx.x & 63) == 0){
            int im12 = (img/5)*4 + (n-1);
            atomicMin(&misc[im12], f2ord(vmin));
            atomicMax(&misc[12+im12], f2ord(vmax));
        }
    }
}

__global__ __launch_bounds__(256) void k_ent(const float* __restrict__ com,
        float* __restrict__ ent)
{
    int img = blockIdx.y;
    int p = blockIdx.x*256 + threadIdx.x;
    if (p >= PP) return;
    int off[9]; bool val[9];
    tap_setup(p, off, val);
    const float* s = com + (size_t)img*PP;
    float x = s[p];
    float v[9];
#pragma unroll
    for (int t=0;t<9;t++) v[t] = s[off[t]];
    float acc = 0.0f;
#pragma unroll
    for (int t=0;t<9;t++){
        float xv = val[t] ? v[t] : 0.0f;
        acc += 1.0f/(1.0f + expf(x - xv));
    }
    ent[(size_t)img*PP + p] = acc / 9.0f;
}

// big path: mask + per-block partial count (no hot atomic)
__global__ __launch_bounds__(256) void k_maskp(const float* __restrict__ ent,
        float* __restrict__ maskb, unsigned* __restrict__ partial)
{
    __shared__ unsigned cnt[4];
    int im12 = blockIdx.y; int bt = im12 >> 2; int n = (im12 & 3) + 1;
    int p = blockIdx.x*256 + threadIdx.x;
    int v = 0;
    if (p < PP){
        float en = ent[(size_t)(bt*5+n)*PP + p];
        float et = ent[(size_t)(bt*5)*PP + p];
        v = en > et;
        maskb[(size_t)im12*PP + p] = (float)v;
    }
    unsigned long long bal = __ballot(v);
    if ((threadIdx.x & 63) == 0) cnt[threadIdx.x>>6] = (unsigned)__popcll(bal);
    __syncthreads();
    if (threadIdx.x == 0)
        partial[blockIdx.y*GX + blockIdx.x] = cnt[0]+cnt[1]+cnt[2]+cnt[3];
}

// FALLBACK mask (atomic)
__global__ __launch_bounds__(256) void k_mask(const float* __restrict__ ent,
        float* __restrict__ maskb, unsigned* __restrict__ misc)
{
    int im12 = blockIdx.y; int bt = im12 >> 2; int n = (im12 & 3) + 1;
    int p = blockIdx.x*256 + threadIdx.x;
    int v = 0;
    if (p < PP){
        float en = ent[(size_t)(bt*5+n)*PP + p];
        float et = ent[(size_t)(bt*5)*PP + p];
        v = en > et;
        maskb[(size_t)im12*PP + p] = (float)v;
    }
    unsigned long long bal = __ballot(v);
    if ((threadIdx.x & 63) == 0) atomicAdd(&misc[24], (unsigned)__popcll(bal));
}

__global__ __launch_bounds__(256) void k_den(const float* __restrict__ maskb,
        float* __restrict__ denb)
{
    int im12 = blockIdx.y;
    int p = blockIdx.x*256 + threadIdx.x;
    if (p >= PP) return;
    int off[9]; bool val[9];
    tap_setup(p, off, val);
    const float* mrow = maskb + (size_t)im12*PP;
    float v[9];
#pragma unroll
    for (int t=0;t<9;t++) v[t] = mrow[off[t]];
    float s = 0.0f;
#pragma unroll
    for (int t=0;t<9;t++) s += val[t] ? v[t] : 0.0f;
    denb[(size_t)im12*PP + p] = s;
}

// big path: finalize iszero + bandwidth from partial counts (1 block, 256 thr)
__global__ __launch_bounds__(256) void k_finp(const unsigned* __restrict__ partial,
        unsigned* misc, float* bwout)
{
    __shared__ unsigned sh[4];
    unsigned s = 0;
    for (int i = threadIdx.x; i < NPART; i += 256) s += partial[i];
#pragma unroll
    for (int sft=32;sft>0;sft>>=1) s += (unsigned)__shfl_xor((int)s, sft, 64);
    if ((threadIdx.x & 63) == 0) sh[threadIdx.x>>6] = s;
    __syncthreads();
    int t = threadIdx.x;
    if (t < 12){
        float mn = ord2f(misc[t]);
        float mx = ord2f(misc[12+t]);
        ((int*)misc)[25+t] = (mn + mx == 0.0f) ? 1 : 0;
    }
    if (t == 12) bwout[0] = (float)(sh[0]+sh[1]+sh[2]+sh[3]) / 480000.0f;
}

// FALLBACK finalize
__global__ void k_fin(unsigned* misc, float* bwout){
    int t = threadIdx.x;
    if (t < 12){
        float mn = ord2f(misc[t]);
        float mx = ord2f(misc[12+t]);
        ((int*)misc)[25+t] = (mn + mx == 0.0f) ? 1 : 0;
    }
    if (t == 12) bwout[0] = (float)misc[24] / 480000.0f;
}

// ---------------------------------------------------------------------------
// k_xtg: Xtg[bt][chunk=8][PP][8] = bf16(tg), LDS transpose.
// grid (625, 3), block 256.
// ---------------------------------------------------------------------------
__global__ __launch_bounds__(256) void k_xtg(const float* __restrict__ bevs,
        short* __restrict__ Xtg)
{
    __shared__ short tile[64][72];     // [px_local][ch], rows 144B (16B-mult)
    int tid = threadIdx.x;
    int bt = blockIdx.y;
    int px0 = blockIdx.x*64;
    const float* tg = bevs + (size_t)bt*5*64*PP;
    int c = tid>>2, q = tid&3;
#pragma unroll
    for (int j=0;j<4;j++){
        int pxl = q*16 + j*4;
        f32x4 v = *(const f32x4*)&tg[(size_t)c*PP + px0 + pxl];
#pragma unroll
        for (int e=0;e<4;e++) tile[pxl+e][c] = f2bf(v[e]);
    }
    __syncthreads();
    int pxl = tid&63, qq = tid>>6;     // qq: 0..3 -> chunks 2qq, 2qq+1
    short* base = Xtg + (size_t)bt*PP*64;
    *(bf16x8*)&base[((size_t)(2*qq  )*PP + px0 + pxl)*8] = *(bf16x8*)&tile[pxl][qq*16];
    *(bf16x8*)&base[((size_t)(2*qq+1)*PP + px0 + pxl)*8] = *(bf16x8*)&tile[pxl][qq*16+8];
}

// ---------------------------------------------------------------------------
// k_xft (r16 direct-load body, measured 85.7us, + launch_bounds(256,5) to
// unlock 5 waves/SIMD: VGPR cap 102, body needs ~104 -> 2 regs of slack).
// Xft[im12][chunk=8][PP][8]. Thread: 4 consecutive px x 8 ch; 3x f32x4
// row-window loads; den inline (exact 0/1 sum). grid (40, 12, 8), block 256.
// ---------------------------------------------------------------------------
__global__ __launch_bounds__(256,5) void k_xft(const float* __restrict__ bevs,
        const float* __restrict__ maskb,
        const unsigned* __restrict__ misc, short* __restrict__ Xft)
{
    int im12 = blockIdx.y; int bt = im12 >> 2; int n = (im12 & 3) + 1;
    int chunk = blockIdx.z;
    int chb = chunk*8;
    int idx = blockIdx.x*256 + threadIdx.x;
    if (idx >= PP/4) return;
    int p = idx*4;
    int row = p / WDIM, col0 = p - row*WDIM;
    int s0 = max(col0-4, 0), s2 = min(col0+4, WDIM-4);
    int rowc[3]; bool rowok[3];
#pragma unroll
    for (int r=0;r<3;r++){
        int rr = row + r - 1;
        rowok[r] = (rr>=0) && (rr<HDIM);
        rowc[r] = min(max(rr,0),HDIM-1) * WDIM;
    }
    bool colok[6];
#pragma unroll
    for (int k=0;k<6;k++){
        int cc = col0 + k - 1;
        colok[k] = (cc>=0) && (cc<WDIM);
    }
    const float* mrow = maskb + (size_t)im12*PP;
    float m6[3][6];
#pragma unroll
    for (int r=0;r<3;r++){
        f32x4 a0 = *(const f32x4*)&mrow[rowc[r] + s0];
        f32x4 a1 = *(const f32x4*)&mrow[rowc[r] + col0];
        f32x4 a2 = *(const f32x4*)&mrow[rowc[r] + s2];
        float mv[6] = {a0[3], a1[0], a1[1], a1[2], a1[3], a2[0]};
#pragma unroll
        for (int k=0;k<6;k++)
            m6[r][k] = (rowok[r] && colok[k]) ? mv[k] : 0.0f;
    }
    // den inline: exact 0/1 sum, replaces k_den + denb read
    float rden[4];
#pragma unroll
    for (int j=0;j<4;j++){
        float d = 0.0f;
#pragma unroll
        for (int r=0;r<3;r++){
#pragma unroll
            for (int dk=0;dk<3;dk++) d += m6[r][j+dk];
        }
        rden[j] = 1.0f/(d + NEPS);
    }
    int iz = ((const int*)misc)[25+im12];
    const float* nbb = bevs + (size_t)(bt*5+n)*64*PP;

    short fv0[8], fv1[8], fv2[8], fv3[8];
#pragma unroll
    for (int ci=0;ci<8;ci++){
        int c = chb + ci;
        const float* sc = nbb + (size_t)c*PP;
        f32x4 v0[3], v1[3], v2[3];
#pragma unroll
        for (int r=0;r<3;r++){
            v0[r] = *(const f32x4*)&sc[rowc[r] + s0];
            v1[r] = *(const f32x4*)&sc[rowc[r] + col0];
            v2[r] = *(const f32x4*)&sc[rowc[r] + s2];
        }
        float num[4];
#pragma unroll
        for (int j=0;j<4;j++) num[j] = 0.0f;
#pragma unroll
        for (int r=0;r<3;r++){
            float vv[6] = {v0[r][3], v1[r][0], v1[r][1], v1[r][2], v1[r][3], v2[r][0]};
#pragma unroll
            for (int j=0;j<4;j++){
#pragma unroll
                for (int dk=0;dk<3;dk++)
                    num[j] = fmaf(m6[r][j+dk], vv[j+dk], num[j]);
            }
        }
        short out4[4];
#pragma unroll
        for (int j=0;j<4;j++){
            float center = v1[1][j];
            float mc = m6[1][j+1];
            float xc = iz ? center : fmaf(mc, center, (1.0f-mc)*(num[j]*rden[j]));
            out4[j] = f2bf(xc);
        }
        fv0[ci]=out4[0]; fv1[ci]=out4[1]; fv2[ci]=out4[2]; fv3[ci]=out4[3];
    }
    short* xc0 = Xft + (size_t)im12*PP*64 + ((size_t)chunk*PP + p)*8;
    *(bf16x8*)&xc0[0]  = *(bf16x8*)&fv0[0];
    *(bf16x8*)&xc0[8]  = *(bf16x8*)&fv1[0];
    *(bf16x8*)&xc0[16] = *(bf16x8*)&fv2[0];
    *(bf16x8*)&xc0[24] = *(bf16x8*)&fv3[0];
}

// ---------------------------------------------------------------------------
// k_mlp: GEMM. W1 staged to LDS via linear bf16x8 copy (fragment-ordered);
// W2 fragments in registers. grid (157, 15), block 256.
// ---------------------------------------------------------------------------
__global__ __launch_bounds__(256) void k_mlp(const short* __restrict__ Xtg,
        const short* __restrict__ Xft, const short* __restrict__ wbf,
        const float* __restrict__ b1, const float* __restrict__ b2,
        const float* __restrict__ w3, const float* __restrict__ b3,
        const float* __restrict__ w4, const float* __restrict__ b4,
        float* __restrict__ logits)
{
    __shared__ __align__(16) short w1t[16384];      // fragment-ordered
    __shared__ __align__(16) short xt2[4*16*136];
    __shared__ __align__(16) float z2[4*16*33];
    __shared__ float b1l[128], b2l[32], b3l[8], w3l[8*33], w4l[8], b4l[1];

    int tid = threadIdx.x;
    int img = blockIdx.y, bt = img/5, n = img%5;

#pragma unroll
    for (int k=0;k<8;k++){
        int i = tid + k*256;
        *(bf16x8*)&w1t[i*8] = *(const bf16x8*)&wbf[i*8];
    }
    if (tid<256) w3l[(tid>>5)*33 + (tid&31)] = w3[tid];
    if (tid<128) b1l[tid]=b1[tid];
    if (tid<32)  b2l[tid]=b2[tid];
    if (tid<8)   b3l[tid]=b3[tid];
    if (tid<8)   w4l[tid]=w4[tid];
    if (tid==0)  b4l[0]=b4[0];

    int w = tid>>6, l = tid&63;
    int ln = l&15, kg = l>>4;

    bf16x8 w2f[2][4];
#pragma unroll
    for (int nt2=0;nt2<2;nt2++)
#pragma unroll
    for (int ks=0;ks<4;ks++)
        w2f[nt2][ks] = *(const bf16x8*)&wbf[16384 + ((nt2*4+ks)*64 + l)*8];

    __syncthreads();

    const short* xtgb = Xtg + (size_t)bt*PP*64;
    const short* xftb = (n>0) ? (Xft + (size_t)(bt*4+n-1)*PP*64) : xtgb;
    short* xt2w = &xt2[w*16*136];
    float* z2w  = &z2[w*16*33];
    int px_base = blockIdx.x*256 + w*64;

#pragma unroll 1
    for (int mt=0; mt<4; mt++){
        int prow = px_base + mt*16;
        int arow = prow + ln; if (arow > PP-1) arow = PP-1;
        bf16x8 af[4];
        af[0] = *(const bf16x8*)&xtgb[((size_t)kg*PP     + arow)*8];
        af[1] = *(const bf16x8*)&xtgb[((size_t)(kg+4)*PP + arow)*8];
        af[2] = *(const bf16x8*)&xftb[((size_t)kg*PP     + arow)*8];
        af[3] = *(const bf16x8*)&xftb[((size_t)(kg+4)*PP + arow)*8];

#pragma unroll
        for (int nt=0;nt<8;nt++){
            float bias = b1l[nt*16 + ln];
            f32x4 acc = {bias, bias, bias, bias};
#pragma unroll
            for (int ks=0;ks<4;ks++){
                bf16x8 bf = *(const bf16x8*)&w1t[((nt*4+ks)*64 + l)*8];
                acc = __builtin_amdgcn_mfma_f32_16x16x32_bf16(af[ks], bf, acc, 0, 0, 0);
            }
#pragma unroll
            for (int r=0;r<4;r++)
                xt2w[(kg*4+r)*136 + nt*16 + ln] = f2bf(fmaxf(acc[r], 0.0f));
        }

        bf16x8 a2[4];
#pragma unroll
        for (int ks=0;ks<4;ks++)
            a2[ks] = *(const bf16x8*)&xt2w[ln*136 + ks*32 + kg*8];
#pragma unroll
        for (int nt2=0;nt2<2;nt2++){
            float bias = b2l[nt2*16 + ln];
            f32x4 acc = {bias, bias, bias, bias};
#pragma unroll
            for (int ks=0;ks<4;ks++)
                acc = __builtin_amdgcn_mfma_f32_16x16x32_bf16(a2[ks], w2f[nt2][ks], acc, 0, 0, 0);
#pragma unroll
            for (int r=0;r<4;r++)
                z2w[(kg*4+r)*33 + nt2*16 + ln] = fmaxf(acc[r], 0.0f);
        }

        int k0 = kg*2, k1 = kg*2+1;
        float y0 = b3l[k0], y1 = b3l[k1];
#pragma unroll
        for (int j=0;j<32;j++){
            float v = z2w[ln*33 + j];
            y0 = fmaf(w3l[k0*33+j], v, y0);
            y1 = fmaf(w3l[k1*33+j], v, y1);
        }
        float part = w4l[k0]*fmaxf(y0,0.0f) + w4l[k1]*fmaxf(y1,0.0f);
        part += __shfl_xor(part, 16, 64);
        part += __shfl_xor(part, 32, 64);
        if (kg == 0 && prow + ln < PP)
            logits[(size_t)img*PP + prow + ln] = fmaxf(part + b4l[0], 0.0f);
    }
}

// ---------------------------------------------------------------------------
// k_fuse2: softmax + weighted sum (tg fp32 from bevs, warp bf16 from Xft chunks)
// grid (157, 3, 2)
// ---------------------------------------------------------------------------
__global__ __launch_bounds__(256) void k_fuse2(const float* __restrict__ bevs,
        const float* __restrict__ logits, const short* __restrict__ Xft,
        float* __restrict__ out)
{
    int bt = blockIdx.y;
    int cb = blockIdx.z*32;
    int chunk0 = cb>>3;
    int p = blockIdx.x*256 + threadIdx.x;
    if (p >= PP) return;
    float e[5], ssum = 0.0f;
#pragma unroll
    for (int nn=0;nn<5;nn++){ e[nn] = expf(logits[(size_t)(bt*5+nn)*PP + p]); ssum += e[nn]; }
    float rs = 1.0f/ssum;
    const float* tgb = bevs + (size_t)bt*5*64*PP;
    float acc[32];
    float w0 = e[0]*rs;
#pragma unroll
    for (int ci=0;ci<32;ci++) acc[ci] = w0*tgb[(size_t)(cb+ci)*PP + p];
#pragma unroll
    for (int k=0;k<4;k++){
        float wk = e[k+1]*rs;
        const short* Xim = Xft + (size_t)(bt*4+k)*PP*64;
#pragma unroll
        for (int c8=0;c8<4;c8++){
            bf16x8 v = *(const bf16x8*)&Xim[((size_t)(chunk0+c8)*PP + p)*8];
#pragma unroll
            for (int j=0;j<8;j++)
                acc[c8*8+j] = fmaf(wk, bf2f(v[j]), acc[c8*8+j]);
        }
    }
#pragma unroll
    for (int ci=0;ci<32;ci++)
        out[((size_t)bt*64 + cb+ci)*PP + p] = acc[ci];
}

// ---------------------------------------------------------------------------
// FALLBACK path (fused kernels) if ws too small
// ---------------------------------------------------------------------------
__global__ __launch_bounds__(256) void k_pwf(const float* __restrict__ bevs,
        const float* __restrict__ w1, const float* __restrict__ b1,
        const float* __restrict__ w2, const float* __restrict__ b2,
        const float* __restrict__ w3, const float* __restrict__ b3,
        const float* __restrict__ w4, const float* __restrict__ b4,
        const float* __restrict__ maskb, const float* __restrict__ denb,
        const unsigned* __restrict__ misc, float* __restrict__ logits)
{
    __shared__ __align__(16) short w1t[128*136];
    __shared__ __align__(16) short w2t[32*136];
    __shared__ __align__(16) short xt[64*136];
    __shared__ __align__(16) float z2[64*33];
    __shared__ float b1l[128], b2l[32], b3l[8], w3l[256], w4l[8], b4l[1];

    int tid = threadIdx.x;
    int img = blockIdx.y, bt = img/5, n = img%5;

    for (int i=tid;i<16384;i+=256) w1t[(i>>7)*136 + (i&127)] = f2bf(w1[i]);
    for (int i=tid;i<4096;i+=256)  w2t[(i>>7)*136 + (i&127)] = f2bf(w2[i]);
    if (tid<128) b1l[tid]=b1[tid];
    if (tid<32)  b2l[tid]=b2[tid];
    if (tid<8)   b3l[tid]=b3[tid];
    if (tid<256) w3l[tid]=w3[tid];
    if (tid<8)   w4l[tid]=w4[tid];
    if (tid==0)  b4l[0]=b4[0];

    int px = tid&63, q = tid>>6;
    int p = blockIdx.x*64 + px;
    const float* tg = bevs + (size_t)bt*5*64*PP;
    if (n == 0){
#pragma unroll
        for (int ci=0;ci<16;ci++){
            int c = q*16+ci;
            short v = f2bf(tg[(size_t)c*PP + p]);
            xt[px*136 + c] = v;
            xt[px*136 + 64 + c] = v;
        }
    } else {
        int im12 = bt*4 + (n-1);
        int off[9]; bool val[9];
        tap_setup(p, off, val);
        const float* mrow = maskb + (size_t)im12*PP;
        float m9[9];
#pragma unroll
        for (int t=0;t<9;t++) m9[t] = val[t] ? mrow[off[t]] : 0.0f;
        float rden = 1.0f/(denb[(size_t)im12*PP + p] + NEPS);
        int iz = ((const int*)misc)[25+im12];
        float mc = m9[4];
        const float* nbb = bevs + (size_t)(bt*5+n)*64*PP;
#pragma unroll
        for (int ci=0;ci<16;ci++){
            int c = q*16+ci;
            xt[px*136 + c] = f2bf(tg[(size_t)c*PP + p]);
            const float* sc = nbb + (size_t)c*PP;
            float num = 0.0f, center = 0.0f;
#pragma unroll
            for (int t=0;t<9;t++){
                if (val[t]){
                    float v = sc[off[t]];
                    num = fmaf(m9[t], v, num);
                    if (t==4) center = v;
                }
            }
            float xc = iz ? center : fmaf(mc, center, (1.0f-mc)*(num*rden));
            xt[px*136 + 64 + c] = f2bf(xc);
        }
    }
    __syncthreads();

    int w = tid>>6, l = tid&63;
    int ln = l&15, kg = l>>4;
    bf16x8 af[4];
#pragma unroll
    for (int ks=0;ks<4;ks++)
        af[ks] = *(const bf16x8*)&xt[(w*16+ln)*136 + ks*32 + kg*8];
#pragma unroll
    for (int nt=0;nt<8;nt++){
        float bias = b1l[nt*16 + ln];
        f32x4 acc = {bias, bias, bias, bias};
#pragma unroll
        for (int ks=0;ks<4;ks++){
            bf16x8 bf = *(const bf16x8*)&w1t[(nt*16+ln)*136 + ks*32 + kg*8];
            acc = __builtin_amdgcn_mfma_f32_16x16x32_bf16(af[ks], bf, acc, 0, 0, 0);
        }
#pragma unroll
        for (int r=0;r<4;r++){
            int pr = w*16 + kg*4 + r;
            xt[pr*136 + nt*16 + ln] = f2bf(fmaxf(acc[r], 0.0f));
        }
    }
    bf16x8 a2[4];
#pragma unroll
    for (int ks=0;ks<4;ks++)
        a2[ks] = *(const bf16x8*)&xt[(w*16+ln)*136 + ks*32 + kg*8];
#pragma unroll
    for (int nt2=0;nt2<2;nt2++){
        float bias = b2l[nt2*16 + ln];
        f32x4 acc = {bias, bias, bias, bias};
#pragma unroll
        for (int ks=0;ks<4;ks++){
            bf16x8 bf = *(const bf16x8*)&w2t[(nt2*16+ln)*136 + ks*32 + kg*8];
            acc = __builtin_amdgcn_mfma_f32_16x16x32_bf16(a2[ks], bf, acc, 0, 0, 0);
        }
#pragma unroll
        for (int r=0;r<4;r++){
            int pr = w*16 + kg*4 + r;
            z2[pr*33 + nt2*16 + ln] = fmaxf(acc[r], 0.0f);
        }
    }
    __syncthreads();
    if (tid < 64){
        float y3[8];
#pragma unroll
        for (int k=0;k<8;k++) y3[k] = b3l[k];
        for (int j=0;j<32;j++){
            float v = z2[tid*33 + j];
#pragma unroll
            for (int k=0;k<8;k++) y3[k] = fmaf(w3l[k*32+j], v, y3[k]);
        }
        float sres = b4l[0];
#pragma unroll
        for (int k=0;k<8;k++) sres = fmaf(w4l[k], fmaxf(y3[k], 0.0f), sres);
        logits[(size_t)img*PP + blockIdx.x*64 + tid] = fmaxf(sres, 0.0f);
    }
}

__global__ __launch_bounds__(256) void k_fuse_old(const float* __restrict__ bevs,
        const float* __restrict__ logits, const float* __restrict__ maskb,
        const float* __restrict__ denb, const unsigned* __restrict__ misc,
        float* __restrict__ out)
{
    int bt = blockIdx.y;
    int p = blockIdx.x*256 + threadIdx.x;
    if (p >= PP) return;
    int off[9]; bool val[9];
    tap_setup(p, off, val);
    float e[5], ssum = 0.0f;
#pragma unroll
    for (int nn=0;nn<5;nn++){ e[nn] = expf(logits[(size_t)(bt*5+nn)*PP + p]); ssum += e[nn]; }
    float wts[5];
#pragma unroll
    for (int nn=0;nn<5;nn++) wts[nn] = e[nn] / ssum;
    float m9[4][9]; float rden[4]; int iz[4];
#pragma unroll
    for (int k=0;k<4;k++){
        int im12 = bt*4 + k;
        const float* mrow = maskb + (size_t)im12*PP;
#pragma unroll
        for (int t=0;t<9;t++) m9[k][t] = val[t] ? mrow[off[t]] : 0.0f;
        rden[k] = 1.0f/(denb[(size_t)im12*PP + p] + NEPS);
        iz[k] = ((const int*)misc)[25+im12];
    }
    const float* base = bevs + (size_t)bt*5*64*PP;
    for (int c=0;c<64;c++){
        float tgc = base[(size_t)c*PP + p];
        float fused = wts[0]*tgc;
#pragma unroll
        for (int k=0;k<4;k++){
            const float* sc = base + (size_t)(k+1)*64*PP + (size_t)c*PP;
            float num = 0.0f, center = 0.0f;
#pragma unroll
            for (int t=0;t<9;t++){
                if (val[t]){
                    float v = sc[off[t]];
                    num = fmaf(m9[k][t], v, num);
                    if (t==4) center = v;
                }
            }
            float mc = m9[k][4];
            float xc = iz[k] ? center : fmaf(mc, center, (1.0f-mc)*(num*rden[k]));
            fused = fmaf(wts[k+1], xc, fused);
        }
        out[((size_t)bt*64 + c)*PP + p] = fused;
    }
}

extern "C" void kernel_launch(void* const* d_in, const int* in_sizes, int n_in,
                              void* d_out, int out_size, void* d_ws, size_t ws_size,
                              hipStream_t stream)
{
    const float* bevs = (const float*)d_in[0];
    const float* cw  = (const float*)d_in[1];
    const float* cb  = (const float*)d_in[2];
    const float* w1  = (const float*)d_in[3];
    const float* b1  = (const float*)d_in[4];
    const float* w2  = (const float*)d_in[5];
    const float* b2  = (const float*)d_in[6];
    const float* w3  = (const float*)d_in[7];
    const float* b3  = (const float*)d_in[8];
    const float* w4  = (const float*)d_in[9];
    const float* b4  = (const float*)d_in[10];
    float* out = (float*)d_out;
    float* ws = (float*)d_ws;

    float* com    = ws + OFF_COM;
    float* ent    = ws + OFF_ENT;
    float* maskb  = ws + OFF_MASK;
    float* denb   = ws + OFF_DEN;
    float* logits = ws + OFF_LOGITS;
    unsigned* misc = (unsigned*)(ws + OFF_MISC);
    short* Xtg    = (short*)(ws + OFF_XTG_F);
    short* Xft    = (short*)(ws + OFF_XFT_F);
    short* wbf    = (short*)(ws + OFF_WBF_F);
    unsigned* cntp = (unsigned*)(ws + OFF_CNT_F);
    float* z      = (float*)(ws + OFF_XFT_F);   // overlaps Xft; dead before Xft written

    dim3 blk(256,1,1);
    int gx = GX;
    bool big = ws_size >= WS_NEED;

    k_init<<<dim3(1),dim3(64),0,stream>>>(misc);
    if (big){
        k_wcvt<<<dim3(80),blk,0,stream>>>(w1,w2,wbf);
        k_csum<<<dim3((PP/4+255)/256,15),blk,0,stream>>>(bevs,cw,misc,z);
        k_cfin<<<dim3(gx,15),blk,0,stream>>>(z,cb,com);
        k_xtg <<<dim3(PP/64,3),blk,0,stream>>>(bevs,Xtg);
    } else {
        k_conv<<<dim3(gx,15),blk,0,stream>>>(bevs,cw,cb,com,misc);
    }
    k_ent <<<dim3(gx,15),blk,0,stream>>>(com,ent);
    if (big){
        k_maskp<<<dim3(gx,12),blk,0,stream>>>(ent,maskb,cntp);
        k_finp<<<dim3(1),blk,0,stream>>>(cntp, misc, out + (size_t)3*64*PP);
        k_xft  <<<dim3((PP/4+255)/256,12,8),blk,0,stream>>>(bevs,maskb,misc,Xft);
        k_mlp  <<<dim3(gx,15),blk,0,stream>>>(Xtg,Xft,wbf,b1,b2,w3,b3,w4,b4,logits);
        k_fuse2<<<dim3(gx,3,2),blk,0,stream>>>(bevs,logits,Xft,out);
    } else {
        k_mask<<<dim3(gx,12),blk,0,stream>>>(ent,maskb,misc);
        k_den <<<dim3(gx,12),blk,0,stream>>>(maskb,denb);
        k_fin <<<dim3(1),dim3(64),0,stream>>>(misc, out + (size_t)3*64*PP);
        k_pwf  <<<dim3(PP/64,15),blk,0,stream>>>(bevs,w1,b1,w2,b2,w3,b3,w4,b4,maskb,denb,misc,logits);
        k_fuse_old<<<dim3(gx,3),blk,0,stream>>>(bevs,logits,maskb,denb,misc,out);
    }
}

// Round 23
// 244.521 us; speedup vs baseline: 2.2635x; 2.2635x over previous
//
#include <hip/hip_runtime.h>
#include <hip/hip_bf16.h>
#include <math.h>

#define PP 40000
#define HDIM 200
#define WDIM 200
#define NEPS 1e-8f
#define GX 157                 // (PP+255)/256
#define NPART (GX*12)

// workspace layout (float offsets)
#define OFF_COM    0            // 15*PP
#define OFF_ENT    (15*PP)      // 15*PP
#define OFF_MASK   (30*PP)      // 12*PP
#define OFF_DEN    (42*PP)      // 12*PP (fallback path only)
#define OFF_LOGITS (54*PP)      // 15*PP
#define OFF_MISC   (69*PP)      // 64 floats
#define OFF_XTG_F  (69*PP + 64)             // Xtg bf16 [bt][8][PP][8]: 3*PP*64 shorts
#define OFF_XFT_F  (OFF_XTG_F + 3*PP*32)    // Xft bf16 [im12][8][PP][8]: 12*PP*64 shorts; z fp32 (135*PP) overlaps (dead before Xft written)
#define OFF_WBF_F  (OFF_XFT_F + 12*PP*32)   // wbf bf16 FRAGMENT-ORDERED: w1 16384 + w2 4096 shorts
#define OFF_CNT_F  (OFF_WBF_F + 10240)      // partial mask counts: NPART uints
#define WS_NEED ((size_t)(OFF_CNT_F + NPART + 64)*4)

typedef __attribute__((ext_vector_type(8))) short bf16x8;
typedef __attribute__((ext_vector_type(4))) float f32x4;

__device__ __forceinline__ short f2bf(float f){
    __hip_bfloat16 h = __float2bfloat16(f);   // RTNE
    return *reinterpret_cast<short*>(&h);
}
__device__ __forceinline__ float bf2f(short s){
    return __uint_as_float(((unsigned)(unsigned short)s) << 16);
}

__device__ __forceinline__ unsigned f2ord(float f){
    unsigned u = __float_as_uint(f);
    return (u & 0x80000000u) ? ~u : (u | 0x80000000u);
}
__device__ __forceinline__ float ord2f(unsigned u){
    unsigned v = (u & 0x80000000u) ? (u & 0x7fffffffu) : ~u;
    return __uint_as_float(v);
}

// Clamped tap offsets (per-pixel scalar form, used by small kernels)
__device__ __forceinline__ void tap_setup(int p, int* off, bool* val){
    int h = p / WDIM, w = p - h*WDIM;
#pragma unroll
    for (int ky=0;ky<3;ky++)
#pragma unroll
        for (int kx=0;kx<3;kx++){
            int t = ky*3+kx;
            int hh = h+ky-1, ww = w+kx-1;
            val[t] = (hh>=0)&&(hh<HDIM)&&(ww>=0)&&(ww<WDIM);
            int hc = min(max(hh,0),HDIM-1);
            int wc = min(max(ww,0),WDIM-1);
            off[t] = hc*WDIM+wc;
        }
}

__global__ void k_init(unsigned* misc){
    int t = threadIdx.x;
    if (t < 12) misc[t] = 0xFFFFFFFFu;        // min (sortable) = +inf
    else if (t < 25) misc[t] = 0u;            // max = -inf, count = 0
}

// one-shot fp32 -> bf16 weight conversion into MFMA FRAGMENT ORDER:
// wbf[((nt*4+ks)*64 + lane)*8 + e], lane = kg*16+ln
__global__ __launch_bounds__(256) void k_wcvt(const float* __restrict__ w1,
        const float* __restrict__ w2, short* __restrict__ wbf)
{
    int i = blockIdx.x*256 + threadIdx.x;
    if (i < 16384){
        int e = i&7, l = (i>>3)&63, ks = (i>>9)&3, nt = i>>11;
        int ln = l&15, kg = l>>4;
        wbf[i] = f2bf(w1[(nt*16+ln)*128 + ks*32 + kg*8 + e]);
    } else if (i < 20480){
        int j = i - 16384;
        int e = j&7, l = (j>>3)&63, ks = (j>>9)&3, nt2 = j>>11;
        int ln = l&15, kg = l>>4;
        wbf[i] = f2bf(w2[(nt2*16+ln)*128 + ks*32 + kg*8 + e]);
    }
}

// ---------------------------------------------------------------------------
// conv pass 1 (4 px/thread, f32x4, unroll 4 -- r21 winner):
// z_t(q) = sum_c w[c,t]*x[c,q]; min/max fused. grid (40, 15), block 256.
// ---------------------------------------------------------------------------
__global__ __launch_bounds__(256) void k_csum(const float* __restrict__ bevs,
        const float* __restrict__ cw, unsigned* __restrict__ misc,
        float* __restrict__ z)
{
    int img = blockIdx.y;
    int n = img % 5;
    int idx = blockIdx.x*256 + threadIdx.x;
    bool act = idx < PP/4;
    int p = idx*4;
    float vmin = INFINITY, vmax = -INFINITY;
    f32x4 acc[9];
#pragma unroll
    for (int t=0;t<9;t++) acc[t] = (f32x4){0.f,0.f,0.f,0.f};
    if (act){
        const float* src = bevs + (size_t)img*64*PP;
#pragma unroll 4
        for (int c=0;c<64;c++){
            f32x4 v = *(const f32x4*)&src[(size_t)c*PP + p];
            vmin = fminf(fminf(fminf(vmin, v[0]), fminf(v[1], v[2])), v[3]);
            vmax = fmaxf(fmaxf(fmaxf(vmax, v[0]), fmaxf(v[1], v[2])), v[3]);
#pragma unroll
            for (int t=0;t<9;t++){
                float w = cw[c*9+t];
#pragma unroll
                for (int j=0;j<4;j++) acc[t][j] = fmaf(w, v[j], acc[t][j]);
            }
        }
        float* zimg = z + (size_t)img*9*PP;
#pragma unroll
        for (int t=0;t<9;t++)
            *(f32x4*)&zimg[(size_t)t*PP + p] = acc[t];
    }
    if (n > 0){
#pragma unroll
        for (int s=32;s>0;s>>=1){
            vmin = fminf(vmin, __shfl_xor(vmin, s, 64));
            vmax = fmaxf(vmax, __shfl_xor(vmax, s, 64));
        }
        if ((threadIdx.x & 63) == 0){
            int im12 = (img/5)*4 + (n-1);
            atomicMin(&misc[im12], f2ord(vmin));
            atomicMax(&misc[12+im12], f2ord(vmax));
        }
    }
}

// conv pass 2: com(p) = relu(cb + sum_t [val] z_t(p+delta_t))
__global__ __launch_bounds__(256) void k_cfin(const float* __restrict__ z,
        const float* __restrict__ cb, float* __restrict__ com)
{
    int img = blockIdx.y;
    int p = blockIdx.x*256 + threadIdx.x;
    if (p >= PP) return;
    int off[9]; bool val[9];
    tap_setup(p, off, val);
    const float* zimg = z + (size_t)img*9*PP;
    float v[9];
#pragma unroll
    for (int t=0;t<9;t++) v[t] = zimg[(size_t)t*PP + off[t]];
    float acc = cb[0];
#pragma unroll
    for (int t=0;t<9;t++) acc += val[t] ? v[t] : 0.0f;
    com[(size_t)img*PP + p] = fmaxf(acc, 0.0f);
}

// ---------------------------------------------------------------------------
// FALLBACK conv if ws too small
// ---------------------------------------------------------------------------
__global__ __launch_bounds__(256) void k_conv(const float* __restrict__ bevs,
        const float* __restrict__ cw, const float* __restrict__ cb,
        float* __restrict__ com, unsigned* __restrict__ misc)
{
    int img = blockIdx.y;
    int n = img % 5;
    int p = blockIdx.x*256 + threadIdx.x;
    float vmin = INFINITY, vmax = -INFINITY;
    if (p < PP){
        int off[9]; bool val[9];
        tap_setup(p, off, val);
        const float* src = bevs + (size_t)img*64*PP;
        float acc = cb[0];
#pragma unroll 2
        for (int c=0;c<64;c++){
            const float* sc = src + (size_t)c*PP;
            float v[9];
#pragma unroll
            for (int t=0;t<9;t++) v[t] = sc[off[t]];
            vmin = fminf(vmin, v[4]); vmax = fmaxf(vmax, v[4]);
#pragma unroll
            for (int t=0;t<9;t++)
                acc = fmaf(cw[c*9+t], val[t] ? v[t] : 0.0f, acc);
        }
        com[(size_t)img*PP + p] = fmaxf(acc, 0.0f);
    }
    if (n > 0){
#pragma unroll
        for (int s=32;s>0;s>>=1){
            vmin = fminf(vmin, __shfl_xor(vmin, s, 64));
            vmax = fmaxf(vmax, __shfl_xor(vmax, s, 64));
        }
        if ((threadIdx.x & 63) == 0){
            int im12 = (img/5)*4 + (n-1);
            atomicMin(&misc[im12], f2ord(vmin));
            atomicMax(&misc[12+im12], f2ord(vmax));
        }
    }
}

__global__ __launch_bounds__(256) void k_ent(const float* __restrict__ com,
        float* __restrict__ ent)
{
    int img = blockIdx.y;
    int p = blockIdx.x*256 + threadIdx.x;
    if (p >= PP) return;
    int off[9]; bool val[9];
    tap_setup(p, off, val);
    const float* s = com + (size_t)img*PP;
    float x = s[p];
    float v[9];
#pragma unroll
    for (int t=0;t<9;t++) v[t] = s[off[t]];
    float acc = 0.0f;
#pragma unroll
    for (int t=0;t<9;t++){
        float xv = val[t] ? v[t] : 0.0f;
        acc += 1.0f/(1.0f + expf(x - xv));
    }
    ent[(size_t)img*PP + p] = acc / 9.0f;
}

// big path: mask + per-block partial count (no hot atomic)
__global__ __launch_bounds__(256) void k_maskp(const float* __restrict__ ent,
        float* __restrict__ maskb, unsigned* __restrict__ partial)
{
    __shared__ unsigned cnt[4];
    int im12 = blockIdx.y; int bt = im12 >> 2; int n = (im12 & 3) + 1;
    int p = blockIdx.x*256 + threadIdx.x;
    int v = 0;
    if (p < PP){
        float en = ent[(size_t)(bt*5+n)*PP + p];
        float et = ent[(size_t)(bt*5)*PP + p];
        v = en > et;
        maskb[(size_t)im12*PP + p] = (float)v;
    }
    unsigned long long bal = __ballot(v);
    if ((threadIdx.x & 63) == 0) cnt[threadIdx.x>>6] = (unsigned)__popcll(bal);
    __syncthreads();
    if (threadIdx.x == 0)
        partial[blockIdx.y*GX + blockIdx.x] = cnt[0]+cnt[1]+cnt[2]+cnt[3];
}

// FALLBACK mask (atomic)
__global__ __launch_bounds__(256) void k_mask(const float* __restrict__ ent,
        float* __restrict__ maskb, unsigned* __restrict__ misc)
{
    int im12 = blockIdx.y; int bt = im12 >> 2; int n = (im12 & 3) + 1;
    int p = blockIdx.x*256 + threadIdx.x;
    int v = 0;
    if (p < PP){
        float en = ent[(size_t)(bt*5+n)*PP + p];
        float et = ent[(size_t)(bt*5)*PP + p];
        v = en > et;
        maskb[(size_t)im12*PP + p] = (float)v;
    }
    unsigned long long bal = __ballot(v);
    if ((threadIdx.x & 63) == 0) atomicAdd(&misc[24], (unsigned)__popcll(bal));
}

__global__ __launch_bounds__(256) void k_den(const float* __restrict__ maskb,
        float* __restrict__ denb)
{
    int im12 = blockIdx.y;
    int p = blockIdx.x*256 + threadIdx.x;
    if (p >= PP) return;
    int off[9]; bool val[9];
    tap_setup(p, off, val);
    const float* mrow = maskb + (size_t)im12*PP;
    float v[9];
#pragma unroll
    for (int t=0;t<9;t++) v[t] = mrow[off[t]];
    float s = 0.0f;
#pragma unroll
    for (int t=0;t<9;t++) s += val[t] ? v[t] : 0.0f;
    denb[(size_t)im12*PP + p] = s;
}

// big path: finalize iszero + bandwidth from partial counts (1 block, 256 thr)
__global__ __launch_bounds__(256) void k_finp(const unsigned* __restrict__ partial,
        unsigned* misc, float* bwout)
{
    __shared__ unsigned sh[4];
    unsigned s = 0;
    for (int i = threadIdx.x; i < NPART; i += 256) s += partial[i];
#pragma unroll
    for (int sft=32;sft>0;sft>>=1) s += (unsigned)__shfl_xor((int)s, sft, 64);
    if ((threadIdx.x & 63) == 0) sh[threadIdx.x>>6] = s;
    __syncthreads();
    int t = threadIdx.x;
    if (t < 12){
        float mn = ord2f(misc[t]);
        float mx = ord2f(misc[12+t]);
        ((int*)misc)[25+t] = (mn + mx == 0.0f) ? 1 : 0;
    }
    if (t == 12) bwout[0] = (float)(sh[0]+sh[1]+sh[2]+sh[3]) / 480000.0f;
}

// FALLBACK finalize
__global__ void k_fin(unsigned* misc, float* bwout){
    int t = threadIdx.x;
    if (t < 12){
        float mn = ord2f(misc[t]);
        float mx = ord2f(misc[12+t]);
        ((int*)misc)[25+t] = (mn + mx == 0.0f) ? 1 : 0;
    }
    if (t == 12) bwout[0] = (float)misc[24] / 480000.0f;
}

// ---------------------------------------------------------------------------
// k_xtg: Xtg[bt][chunk=8][PP][8] = bf16(tg), LDS transpose.
// grid (625, 3), block 256.
// ---------------------------------------------------------------------------
__global__ __launch_bounds__(256) void k_xtg(const float* __restrict__ bevs,
        short* __restrict__ Xtg)
{
    __shared__ short tile[64][72];     // [px_local][ch], rows 144B (16B-mult)
    int tid = threadIdx.x;
    int bt = blockIdx.y;
    int px0 = blockIdx.x*64;
    const float* tg = bevs + (size_t)bt*5*64*PP;
    int c = tid>>2, q = tid&3;
#pragma unroll
    for (int j=0;j<4;j++){
        int pxl = q*16 + j*4;
        f32x4 v = *(const f32x4*)&tg[(size_t)c*PP + px0 + pxl];
#pragma unroll
        for (int e=0;e<4;e++) tile[pxl+e][c] = f2bf(v[e]);
    }
    __syncthreads();
    int pxl = tid&63, qq = tid>>6;     // qq: 0..3 -> chunks 2qq, 2qq+1
    short* base = Xtg + (size_t)bt*PP*64;
    *(bf16x8*)&base[((size_t)(2*qq  )*PP + px0 + pxl)*8] = *(bf16x8*)&tile[pxl][qq*16];
    *(bf16x8*)&base[((size_t)(2*qq+1)*PP + px0 + pxl)*8] = *(bf16x8*)&tile[pxl][qq*16+8];
}

// ---------------------------------------------------------------------------
// k_xft (r16 direct-load body, measured 85.7us @ VGPR 104, 4 waves/SIMD).
// NOTE: do NOT add a min-waves launch_bounds here -- capping below the
// body's ~104-VGPR footprint makes the allocator spill wholesale
// (r15: VGPR 48 / WRITE 364MB; r22: VGPR 48 / WRITE 686MB).
// Xft[im12][chunk=8][PP][8]. Thread: 4 consecutive px x 8 ch; 3x f32x4
// row-window loads; den inline (exact 0/1 sum). grid (40, 12, 8), block 256.
// ---------------------------------------------------------------------------
__global__ __launch_bounds__(256) void k_xft(const float* __restrict__ bevs,
        const float* __restrict__ maskb,
        const unsigned* __restrict__ misc, short* __restrict__ Xft)
{
    int im12 = blockIdx.y; int bt = im12 >> 2; int n = (im12 & 3) + 1;
    int chunk = blockIdx.z;
    int chb = chunk*8;
    int idx = blockIdx.x*256 + threadIdx.x;
    if (idx >= PP/4) return;
    int p = idx*4;
    int row = p / WDIM, col0 = p - row*WDIM;
    int s0 = max(col0-4, 0), s2 = min(col0+4, WDIM-4);
    int rowc[3]; bool rowok[3];
#pragma unroll
    for (int r=0;r<3;r++){
        int rr = row + r - 1;
        rowok[r] = (rr>=0) && (rr<HDIM);
        rowc[r] = min(max(rr,0),HDIM-1) * WDIM;
    }
    bool colok[6];
#pragma unroll
    for (int k=0;k<6;k++){
        int cc = col0 + k - 1;
        colok[k] = (cc>=0) && (cc<WDIM);
    }
    const float* mrow = maskb + (size_t)im12*PP;
    float m6[3][6];
#pragma unroll
    for (int r=0;r<3;r++){
        f32x4 a0 = *(const f32x4*)&mrow[rowc[r] + s0];
        f32x4 a1 = *(const f32x4*)&mrow[rowc[r] + col0];
        f32x4 a2 = *(const f32x4*)&mrow[rowc[r] + s2];
        float mv[6] = {a0[3], a1[0], a1[1], a1[2], a1[3], a2[0]};
#pragma unroll
        for (int k=0;k<6;k++)
            m6[r][k] = (rowok[r] && colok[k]) ? mv[k] : 0.0f;
    }
    // den inline: exact 0/1 sum, replaces k_den + denb read
    float rden[4];
#pragma unroll
    for (int j=0;j<4;j++){
        float d = 0.0f;
#pragma unroll
        for (int r=0;r<3;r++){
#pragma unroll
            for (int dk=0;dk<3;dk++) d += m6[r][j+dk];
        }
        rden[j] = 1.0f/(d + NEPS);
    }
    int iz = ((const int*)misc)[25+im12];
    const float* nbb = bevs + (size_t)(bt*5+n)*64*PP;

    short fv0[8], fv1[8], fv2[8], fv3[8];
#pragma unroll
    for (int ci=0;ci<8;ci++){
        int c = chb + ci;
        const float* sc = nbb + (size_t)c*PP;
        f32x4 v0[3], v1[3], v2[3];
#pragma unroll
        for (int r=0;r<3;r++){
            v0[r] = *(const f32x4*)&sc[rowc[r] + s0];
            v1[r] = *(const f32x4*)&sc[rowc[r] + col0];
            v2[r] = *(const f32x4*)&sc[rowc[r] + s2];
        }
        float num[4];
#pragma unroll
        for (int j=0;j<4;j++) num[j] = 0.0f;
#pragma unroll
        for (int r=0;r<3;r++){
            float vv[6] = {v0[r][3], v1[r][0], v1[r][1], v1[r][2], v1[r][3], v2[r][0]};
#pragma unroll
            for (int j=0;j<4;j++){
#pragma unroll
                for (int dk=0;dk<3;dk++)
                    num[j] = fmaf(m6[r][j+dk], vv[j+dk], num[j]);
            }
        }
        short out4[4];
#pragma unroll
        for (int j=0;j<4;j++){
            float center = v1[1][j];
            float mc = m6[1][j+1];
            float xc = iz ? center : fmaf(mc, center, (1.0f-mc)*(num[j]*rden[j]));
            out4[j] = f2bf(xc);
        }
        fv0[ci]=out4[0]; fv1[ci]=out4[1]; fv2[ci]=out4[2]; fv3[ci]=out4[3];
    }
    short* xc0 = Xft + (size_t)im12*PP*64 + ((size_t)chunk*PP + p)*8;
    *(bf16x8*)&xc0[0]  = *(bf16x8*)&fv0[0];
    *(bf16x8*)&xc0[8]  = *(bf16x8*)&fv1[0];
    *(bf16x8*)&xc0[16] = *(bf16x8*)&fv2[0];
    *(bf16x8*)&xc0[24] = *(bf16x8*)&fv3[0];
}

// ---------------------------------------------------------------------------
// k_mlp: GEMM. W1 staged to LDS via linear bf16x8 copy (fragment-ordered);
// W2 fragments in registers. grid (157, 15), block 256.
// ---------------------------------------------------------------------------
__global__ __launch_bounds__(256) void k_mlp(const short* __restrict__ Xtg,
        const short* __restrict__ Xft, const short* __restrict__ wbf,
        const float* __restrict__ b1, const float* __restrict__ b2,
        const float* __restrict__ w3, const float* __restrict__ b3,
        const float* __restrict__ w4, const float* __restrict__ b4,
        float* __restrict__ logits)
{
    __shared__ __align__(16) short w1t[16384];      // fragment-ordered
    __shared__ __align__(16) short xt2[4*16*136];
    __shared__ __align__(16) float z2[4*16*33];
    __shared__ float b1l[128], b2l[32], b3l[8], w3l[8*33], w4l[8], b4l[1];

    int tid = threadIdx.x;
    int img = blockIdx.y, bt = img/5, n = img%5;

#pragma unroll
    for (int k=0;k<8;k++){
        int i = tid + k*256;
        *(bf16x8*)&w1t[i*8] = *(const bf16x8*)&wbf[i*8];
    }
    if (tid<256) w3l[(tid>>5)*33 + (tid&31)] = w3[tid];
    if (tid<128) b1l[tid]=b1[tid];
    if (tid<32)  b2l[tid]=b2[tid];
    if (tid<8)   b3l[tid]=b3[tid];
    if (tid<8)   w4l[tid]=w4[tid];
    if (tid==0)  b4l[0]=b4[0];

    int w = tid>>6, l = tid&63;
    int ln = l&15, kg = l>>4;

    bf16x8 w2f[2][4];
#pragma unroll
    for (int nt2=0;nt2<2;nt2++)
#pragma unroll
    for (int ks=0;ks<4;ks++)
        w2f[nt2][ks] = *(const bf16x8*)&wbf[16384 + ((nt2*4+ks)*64 + l)*8];

    __syncthreads();

    const short* xtgb = Xtg + (size_t)bt*PP*64;
    const short* xftb = (n>0) ? (Xft + (size_t)(bt*4+n-1)*PP*64) : xtgb;
    short* xt2w = &xt2[w*16*136];
    float* z2w  = &z2[w*16*33];
    int px_base = blockIdx.x*256 + w*64;

#pragma unroll 1
    for (int mt=0; mt<4; mt++){
        int prow = px_base + mt*16;
        int arow = prow + ln; if (arow > PP-1) arow = PP-1;
        bf16x8 af[4];
        af[0] = *(const bf16x8*)&xtgb[((size_t)kg*PP     + arow)*8];
        af[1] = *(const bf16x8*)&xtgb[((size_t)(kg+4)*PP + arow)*8];
        af[2] = *(const bf16x8*)&xftb[((size_t)kg*PP     + arow)*8];
        af[3] = *(const bf16x8*)&xftb[((size_t)(kg+4)*PP + arow)*8];

#pragma unroll
        for (int nt=0;nt<8;nt++){
            float bias = b1l[nt*16 + ln];
            f32x4 acc = {bias, bias, bias, bias};
#pragma unroll
            for (int ks=0;ks<4;ks++){
                bf16x8 bf = *(const bf16x8*)&w1t[((nt*4+ks)*64 + l)*8];
                acc = __builtin_amdgcn_mfma_f32_16x16x32_bf16(af[ks], bf, acc, 0, 0, 0);
            }
#pragma unroll
            for (int r=0;r<4;r++)
                xt2w[(kg*4+r)*136 + nt*16 + ln] = f2bf(fmaxf(acc[r], 0.0f));
        }

        bf16x8 a2[4];
#pragma unroll
        for (int ks=0;ks<4;ks++)
            a2[ks] = *(const bf16x8*)&xt2w[ln*136 + ks*32 + kg*8];
#pragma unroll
        for (int nt2=0;nt2<2;nt2++){
            float bias = b2l[nt2*16 + ln];
            f32x4 acc = {bias, bias, bias, bias};
#pragma unroll
            for (int ks=0;ks<4;ks++)
                acc = __builtin_amdgcn_mfma_f32_16x16x32_bf16(a2[ks], w2f[nt2][ks], acc, 0, 0, 0);
#pragma unroll
            for (int r=0;r<4;r++)
                z2w[(kg*4+r)*33 + nt2*16 + ln] = fmaxf(acc[r], 0.0f);
        }

        int k0 = kg*2, k1 = kg*2+1;
        float y0 = b3l[k0], y1 = b3l[k1];
#pragma unroll
        for (int j=0;j<32;j++){
            float v = z2w[ln*33 + j];
            y0 = fmaf(w3l[k0*33+j], v, y0);
            y1 = fmaf(w3l[k1*33+j], v, y1);
        }
        float part = w4l[k0]*fmaxf(y0,0.0f) + w4l[k1]*fmaxf(y1,0.0f);
        part += __shfl_xor(part, 16, 64);
        part += __shfl_xor(part, 32, 64);
        if (kg == 0 && prow + ln < PP)
            logits[(size_t)img*PP + prow + ln] = fmaxf(part + b4l[0], 0.0f);
    }
}

// ---------------------------------------------------------------------------
// k_fuse2: softmax + weighted sum (tg fp32 from bevs, warp bf16 from Xft chunks)
// grid (157, 3, 2)
// ---------------------------------------------------------------------------
__global__ __launch_bounds__(256) void k_fuse2(const float* __restrict__ bevs,
        const float* __restrict__ logits, const short* __restrict__ Xft,
        float* __restrict__ out)
{
    int bt = blockIdx.y;
    int cb = blockIdx.z*32;
    int chunk0 = cb>>3;
    int p = blockIdx.x*256 + threadIdx.x;
    if (p >= PP) return;
    float e[5], ssum = 0.0f;
#pragma unroll
    for (int nn=0;nn<5;nn++){ e[nn] = expf(logits[(size_t)(bt*5+nn)*PP + p]); ssum += e[nn]; }
    float rs = 1.0f/ssum;
    const float* tgb = bevs + (size_t)bt*5*64*PP;
    float acc[32];
    float w0 = e[0]*rs;
#pragma unroll
    for (int ci=0;ci<32;ci++) acc[ci] = w0*tgb[(size_t)(cb+ci)*PP + p];
#pragma unroll
    for (int k=0;k<4;k++){
        float wk = e[k+1]*rs;
        const short* Xim = Xft + (size_t)(bt*4+k)*PP*64;
#pragma unroll
        for (int c8=0;c8<4;c8++){
            bf16x8 v = *(const bf16x8*)&Xim[((size_t)(chunk0+c8)*PP + p)*8];
#pragma unroll
            for (int j=0;j<8;j++)
                acc[c8*8+j] = fmaf(wk, bf2f(v[j]), acc[c8*8+j]);
        }
    }
#pragma unroll
    for (int ci=0;ci<32;ci++)
        out[((size_t)bt*64 + cb+ci)*PP + p] = acc[ci];
}

// ---------------------------------------------------------------------------
// FALLBACK path (fused kernels) if ws too small
// ---------------------------------------------------------------------------
__global__ __launch_bounds__(256) void k_pwf(const float* __restrict__ bevs,
        const float* __restrict__ w1, const float* __restrict__ b1,
        const float* __restrict__ w2, const float* __restrict__ b2,
        const float* __restrict__ w3, const float* __restrict__ b3,
        const float* __restrict__ w4, const float* __restrict__ b4,
        const float* __restrict__ maskb, const float* __restrict__ denb,
        const unsigned* __restrict__ misc, float* __restrict__ logits)
{
    __shared__ __align__(16) short w1t[128*136];
    __shared__ __align__(16) short w2t[32*136];
    __shared__ __align__(16) short xt[64*136];
    __shared__ __align__(16) float z2[64*33];
    __shared__ float b1l[128], b2l[32], b3l[8], w3l[256], w4l[8], b4l[1];

    int tid = threadIdx.x;
    int img = blockIdx.y, bt = img/5, n = img%5;

    for (int i=tid;i<16384;i+=256) w1t[(i>>7)*136 + (i&127)] = f2bf(w1[i]);
    for (int i=tid;i<4096;i+=256)  w2t[(i>>7)*136 + (i&127)] = f2bf(w2[i]);
    if (tid<128) b1l[tid]=b1[tid];
    if (tid<32)  b2l[tid]=b2[tid];
    if (tid<8)   b3l[tid]=b3[tid];
    if (tid<256) w3l[tid]=w3[tid];
    if (tid<8)   w4l[tid]=w4[tid];
    if (tid==0)  b4l[0]=b4[0];

    int px = tid&63, q = tid>>6;
    int p = blockIdx.x*64 + px;
    const float* tg = bevs + (size_t)bt*5*64*PP;
    if (n == 0){
#pragma unroll
        for (int ci=0;ci<16;ci++){
            int c = q*16+ci;
            short v = f2bf(tg[(size_t)c*PP + p]);
            xt[px*136 + c] = v;
            xt[px*136 + 64 + c] = v;
        }
    } else {
        int im12 = bt*4 + (n-1);
        int off[9]; bool val[9];
        tap_setup(p, off, val);
        const float* mrow = maskb + (size_t)im12*PP;
        float m9[9];
#pragma unroll
        for (int t=0;t<9;t++) m9[t] = val[t] ? mrow[off[t]] : 0.0f;
        float rden = 1.0f/(denb[(size_t)im12*PP + p] + NEPS);
        int iz = ((const int*)misc)[25+im12];
        float mc = m9[4];
        const float* nbb = bevs + (size_t)(bt*5+n)*64*PP;
#pragma unroll
        for (int ci=0;ci<16;ci++){
            int c = q*16+ci;
            xt[px*136 + c] = f2bf(tg[(size_t)c*PP + p]);
            const float* sc = nbb + (size_t)c*PP;
            float num = 0.0f, center = 0.0f;
#pragma unroll
            for (int t=0;t<9;t++){
                if (val[t]){
                    float v = sc[off[t]];
                    num = fmaf(m9[t], v, num);
                    if (t==4) center = v;
                }
            }
            float xc = iz ? center : fmaf(mc, center, (1.0f-mc)*(num*rden));
            xt[px*136 + 64 + c] = f2bf(xc);
        }
    }
    __syncthreads();

    int w = tid>>6, l = tid&63;
    int ln = l&15, kg = l>>4;
    bf16x8 af[4];
#pragma unroll
    for (int ks=0;ks<4;ks++)
        af[ks] = *(const bf16x8*)&xt[(w*16+ln)*136 + ks*32 + kg*8];
#pragma unroll
    for (int nt=0;nt<8;nt++){
        float bias = b1l[nt*16 + ln];
        f32x4 acc = {bias, bias, bias, bias};
#pragma unroll
        for (int ks=0;ks<4;ks++){
            bf16x8 bf = *(const bf16x8*)&w1t[(nt*16+ln)*136 + ks*32 + kg*8];
            acc = __builtin_amdgcn_mfma_f32_16x16x32_bf16(af[ks], bf, acc, 0, 0, 0);
        }
#pragma unroll
        for (int r=0;r<4;r++){
            int pr = w*16 + kg*4 + r;
            xt[pr*136 + nt*16 + ln] = f2bf(fmaxf(acc[r], 0.0f));
        }
    }
    bf16x8 a2[4];
#pragma unroll
    for (int ks=0;ks<4;ks++)
        a2[ks] = *(const bf16x8*)&xt[(w*16+ln)*136 + ks*32 + kg*8];
#pragma unroll
    for (int nt2=0;nt2<2;nt2++){
        float bias = b2l[nt2*16 + ln];
        f32x4 acc = {bias, bias, bias, bias};
#pragma unroll
        for (int ks=0;ks<4;ks++){
            bf16x8 bf = *(const bf16x8*)&w2t[(nt2*16+ln)*136 + ks*32 + kg*8];
            acc = __builtin_amdgcn_mfma_f32_16x16x32_bf16(a2[ks], bf, acc, 0, 0, 0);
        }
#pragma unroll
        for (int r=0;r<4;r++){
            int pr = w*16 + kg*4 + r;
            z2[pr*33 + nt2*16 + ln] = fmaxf(acc[r], 0.0f);
        }
    }
    __syncthreads();
    if (tid < 64){
        float y3[8];
#pragma unroll
        for (int k=0;k<8;k++) y3[k] = b3l[k];
        for (int j=0;j<32;j++){
            float v = z2[tid*33 + j];
#pragma unroll
            for (int k=0;k<8;k++) y3[k] = fmaf(w3l[k*32+j], v, y3[k]);
        }
        float sres = b4l[0];
#pragma unroll
        for (int k=0;k<8;k++) sres = fmaf(w4l[k], fmaxf(y3[k], 0.0f), sres);
        logits[(size_t)img*PP + blockIdx.x*64 + tid] = fmaxf(sres, 0.0f);
    }
}

__global__ __launch_bounds__(256) void k_fuse_old(const float* __restrict__ bevs,
        const float* __restrict__ logits, const float* __restrict__ maskb,
        const float* __restrict__ denb, const unsigned* __restrict__ misc,
        float* __restrict__ out)
{
    int bt = blockIdx.y;
    int p = blockIdx.x*256 + threadIdx.x;
    if (p >= PP) return;
    int off[9]; bool val[9];
    tap_setup(p, off, val);
    float e[5], ssum = 0.0f;
#pragma unroll
    for (int nn=0;nn<5;nn++){ e[nn] = expf(logits[(size_t)(bt*5+nn)*PP + p]); ssum += e[nn]; }
    float wts[5];
#pragma unroll
    for (int nn=0;nn<5;nn++) wts[nn] = e[nn] / ssum;
    float m9[4][9]; float rden[4]; int iz[4];
#pragma unroll
    for (int k=0;k<4;k++){
        int im12 = bt*4 + k;
        const float* mrow = maskb + (size_t)im12*PP;
#pragma unroll
        for (int t=0;t<9;t++) m9[k][t] = val[t] ? mrow[off[t]] : 0.0f;
        rden[k] = 1.0f/(denb[(size_t)im12*PP + p] + NEPS);
        iz[k] = ((const int*)misc)[25+im12];
    }
    const float* base = bevs + (size_t)bt*5*64*PP;
    for (int c=0;c<64;c++){
        float tgc = base[(size_t)c*PP + p];
        float fused = wts[0]*tgc;
#pragma unroll
        for (int k=0;k<4;k++){
            const float* sc = base + (size_t)(k+1)*64*PP + (size_t)c*PP;
            float num = 0.0f, center = 0.0f;
#pragma unroll
            for (int t=0;t<9;t++){
                if (val[t]){
                    float v = sc[off[t]];
                    num = fmaf(m9[k][t], v, num);
                    if (t==4) center = v;
                }
            }
            float mc = m9[k][4];
            float xc = iz[k] ? center : fmaf(mc, center, (1.0f-mc)*(num*rden[k]));
            fused = fmaf(wts[k+1], xc, fused);
        }
        out[((size_t)bt*64 + c)*PP + p] = fused;
    }
}

extern "C" void kernel_launch(void* const* d_in, const int* in_sizes, int n_in,
                              void* d_out, int out_size, void* d_ws, size_t ws_size,
                              hipStream_t stream)
{
    const float* bevs = (const float*)d_in[0];
    const float* cw  = (const float*)d_in[1];
    const float* cb  = (const float*)d_in[2];
    const float* w1  = (const float*)d_in[3];
    const float* b1  = (const float*)d_in[4];
    const float* w2  = (const float*)d_in[5];
    const float* b2  = (const float*)d_in[6];
    const float* w3  = (const float*)d_in[7];
    const float* b3  = (const float*)d_in[8];
    const float* w4  = (const float*)d_in[9];
    const float* b4  = (const float*)d_in[10];
    float* out = (float*)d_out;
    float* ws = (float*)d_ws;

    float* com    = ws + OFF_COM;
    float* ent    = ws + OFF_ENT;
    float* maskb  = ws + OFF_MASK;
    float* denb   = ws + OFF_DEN;
    float* logits = ws + OFF_LOGITS;
    unsigned* misc = (unsigned*)(ws + OFF_MISC);
    short* Xtg    = (short*)(ws + OFF_XTG_F);
    short* Xft    = (short*)(ws + OFF_XFT_F);
    short* wbf    = (short*)(ws + OFF_WBF_F);
    unsigned* cntp = (unsigned*)(ws + OFF_CNT_F);
    float* z      = (float*)(ws + OFF_XFT_F);   // overlaps Xft; dead before Xft written

    dim3 blk(256,1,1);
    int gx = GX;
    bool big = ws_size >= WS_NEED;

    k_init<<<dim3(1),dim3(64),0,stream>>>(misc);
    if (big){
        k_wcvt<<<dim3(80),blk,0,stream>>>(w1,w2,wbf);
        k_csum<<<dim3((PP/4+255)/256,15),blk,0,stream>>>(bevs,cw,misc,z);
        k_cfin<<<dim3(gx,15),blk,0,stream>>>(z,cb,com);
        k_xtg <<<dim3(PP/64,3),blk,0,stream>>>(bevs,Xtg);
    } else {
        k_conv<<<dim3(gx,15),blk,0,stream>>>(bevs,cw,cb,com,misc);
    }
    k_ent <<<dim3(gx,15),blk,0,stream>>>(com,ent);
    if (big){
        k_maskp<<<dim3(gx,12),blk,0,stream>>>(ent,maskb,cntp);
        k_finp<<<dim3(1),blk,0,stream>>>(cntp, misc, out + (size_t)3*64*PP);
        k_xft  <<<dim3((PP/4+255)/256,12,8),blk,0,stream>>>(bevs,maskb,misc,Xft);
        k_mlp  <<<dim3(gx,15),blk,0,stream>>>(Xtg,Xft,wbf,b1,b2,w3,b3,w4,b4,logits);
        k_fuse2<<<dim3(gx,3,2),blk,0,stream>>>(bevs,logits,Xft,out);
    } else {
        k_mask<<<dim3(gx,12),blk,0,stream>>>(ent,maskb,misc);
        k_den <<<dim3(gx,12),blk,0,stream>>>(maskb,denb);
        k_fin <<<dim3(1),dim3(64),0,stream>>>(misc, out + (size_t)3*64*PP);
        k_pwf  <<<dim3(PP/64,15),blk,0,stream>>>(bevs,w1,b1,w2,b2,w3,b3,w4,b4,maskb,denb,misc,logits);
        k_fuse_old<<<dim3(gx,3),blk,0,stream>>>(bevs,logits,maskb,denb,misc,out);
    }
}

// Round 24
// 242.975 us; speedup vs baseline: 2.2779x; 1.0064x over previous
//
#include <hip/hip_runtime.h>
#include <hip/hip_bf16.h>
#include <math.h>

#define PP 40000
#define HDIM 200
#define WDIM 200
#define NEPS 1e-8f
#define GX 157                 // (PP+255)/256
#define NPART (GX*12)

// workspace layout (float offsets)
#define OFF_COM    0            // 15*PP
#define OFF_ENT    (15*PP)      // 15*PP
#define OFF_MASK   (30*PP)      // 12*PP
#define OFF_DEN    (42*PP)      // 12*PP (fallback path only)
#define OFF_LOGITS (54*PP)      // 15*PP
#define OFF_MISC   (69*PP)      // 64 floats
#define OFF_XTG_F  (69*PP + 64)             // Xtg bf16 [bt][8][PP][8]: 3*PP*64 shorts
#define OFF_XFT_F  (OFF_XTG_F + 3*PP*32)    // Xft bf16 [im12][8][PP][8]: 12*PP*64 shorts; z fp32 (135*PP) overlaps (dead before Xft written)
#define OFF_WBF_F  (OFF_XFT_F + 12*PP*32)   // wbf bf16 FRAGMENT-ORDERED: w1 16384 + w2 4096 shorts
#define OFF_CNT_F  (OFF_WBF_F + 10240)      // partial mask counts: NPART uints
#define WS_NEED ((size_t)(OFF_CNT_F + NPART + 64)*4)

typedef __attribute__((ext_vector_type(8))) short bf16x8;
typedef __attribute__((ext_vector_type(4))) float f32x4;

__device__ __forceinline__ short f2bf(float f){
    __hip_bfloat16 h = __float2bfloat16(f);   // RTNE
    return *reinterpret_cast<short*>(&h);
}
__device__ __forceinline__ float bf2f(short s){
    return __uint_as_float(((unsigned)(unsigned short)s) << 16);
}

__device__ __forceinline__ unsigned f2ord(float f){
    unsigned u = __float_as_uint(f);
    return (u & 0x80000000u) ? ~u : (u | 0x80000000u);
}
__device__ __forceinline__ float ord2f(unsigned u){
    unsigned v = (u & 0x80000000u) ? (u & 0x7fffffffu) : ~u;
    return __uint_as_float(v);
}

// Clamped tap offsets (per-pixel scalar form, used by small kernels)
__device__ __forceinline__ void tap_setup(int p, int* off, bool* val){
    int h = p / WDIM, w = p - h*WDIM;
#pragma unroll
    for (int ky=0;ky<3;ky++)
#pragma unroll
        for (int kx=0;kx<3;kx++){
            int t = ky*3+kx;
            int hh = h+ky-1, ww = w+kx-1;
            val[t] = (hh>=0)&&(hh<HDIM)&&(ww>=0)&&(ww<WDIM);
            int hc = min(max(hh,0),HDIM-1);
            int wc = min(max(ww,0),WDIM-1);
            off[t] = hc*WDIM+wc;
        }
}

__global__ void k_init(unsigned* misc){
    int t = threadIdx.x;
    if (t < 12) misc[t] = 0xFFFFFFFFu;        // min (sortable) = +inf
    else if (t < 25) misc[t] = 0u;            // max = -inf, count = 0
}

// one-shot fp32 -> bf16 weight conversion into MFMA FRAGMENT ORDER:
// wbf[((nt*4+ks)*64 + lane)*8 + e], lane = kg*16+ln
__global__ __launch_bounds__(256) void k_wcvt(const float* __restrict__ w1,
        const float* __restrict__ w2, short* __restrict__ wbf)
{
    int i = blockIdx.x*256 + threadIdx.x;
    if (i < 16384){
        int e = i&7, l = (i>>3)&63, ks = (i>>9)&3, nt = i>>11;
        int ln = l&15, kg = l>>4;
        wbf[i] = f2bf(w1[(nt*16+ln)*128 + ks*32 + kg*8 + e]);
    } else if (i < 20480){
        int j = i - 16384;
        int e = j&7, l = (j>>3)&63, ks = (j>>9)&3, nt2 = j>>11;
        int ln = l&15, kg = l>>4;
        wbf[i] = f2bf(w2[(nt2*16+ln)*128 + ks*32 + kg*8 + e]);
    }
}

// ---------------------------------------------------------------------------
// conv pass 1 (4 px/thread, f32x4, unroll 4 -- r21 winner):
// z_t(q) = sum_c w[c,t]*x[c,q]; min/max fused. grid (40, 15), block 256.
// ---------------------------------------------------------------------------
__global__ __launch_bounds__(256) void k_csum(const float* __restrict__ bevs,
        const float* __restrict__ cw, unsigned* __restrict__ misc,
        float* __restrict__ z)
{
    int img = blockIdx.y;
    int n = img % 5;
    int idx = blockIdx.x*256 + threadIdx.x;
    bool act = idx < PP/4;
    int p = idx*4;
    float vmin = INFINITY, vmax = -INFINITY;
    f32x4 acc[9];
#pragma unroll
    for (int t=0;t<9;t++) acc[t] = (f32x4){0.f,0.f,0.f,0.f};
    if (act){
        const float* src = bevs + (size_t)img*64*PP;
#pragma unroll 4
        for (int c=0;c<64;c++){
            f32x4 v = *(const f32x4*)&src[(size_t)c*PP + p];
            vmin = fminf(fminf(fminf(vmin, v[0]), fminf(v[1], v[2])), v[3]);
            vmax = fmaxf(fmaxf(fmaxf(vmax, v[0]), fmaxf(v[1], v[2])), v[3]);
#pragma unroll
            for (int t=0;t<9;t++){
                float w = cw[c*9+t];
#pragma unroll
                for (int j=0;j<4;j++) acc[t][j] = fmaf(w, v[j], acc[t][j]);
            }
        }
        float* zimg = z + (size_t)img*9*PP;
#pragma unroll
        for (int t=0;t<9;t++)
            *(f32x4*)&zimg[(size_t)t*PP + p] = acc[t];
    }
    if (n > 0){
#pragma unroll
        for (int s=32;s>0;s>>=1){
            vmin = fminf(vmin, __shfl_xor(vmin, s, 64));
            vmax = fmaxf(vmax, __shfl_xor(vmax, s, 64));
        }
        if ((threadIdx.x & 63) == 0){
            int im12 = (img/5)*4 + (n-1);
            atomicMin(&misc[im12], f2ord(vmin));
            atomicMax(&misc[12+im12], f2ord(vmax));
        }
    }
}

// conv pass 2: com(p) = relu(cb + sum_t [val] z_t(p+delta_t))
__global__ __launch_bounds__(256) void k_cfin(const float* __restrict__ z,
        const float* __restrict__ cb, float* __restrict__ com)
{
    int img = blockIdx.y;
    int p = blockIdx.x*256 + threadIdx.x;
    if (p >= PP) return;
    int off[9]; bool val[9];
    tap_setup(p, off, val);
    const float* zimg = z + (size_t)img*9*PP;
    float v[9];
#pragma unroll
    for (int t=0;t<9;t++) v[t] = zimg[(size_t)t*PP + off[t]];
    float acc = cb[0];
#pragma unroll
    for (int t=0;t<9;t++) acc += val[t] ? v[t] : 0.0f;
    com[(size_t)img*PP + p] = fmaxf(acc, 0.0f);
}

// ---------------------------------------------------------------------------
// FALLBACK conv if ws too small
// ---------------------------------------------------------------------------
__global__ __launch_bounds__(256) void k_conv(const float* __restrict__ bevs,
        const float* __restrict__ cw, const float* __restrict__ cb,
        float* __restrict__ com, unsigned* __restrict__ misc)
{
    int img = blockIdx.y;
    int n = img % 5;
    int p = blockIdx.x*256 + threadIdx.x;
    float vmin = INFINITY, vmax = -INFINITY;
    if (p < PP){
        int off[9]; bool val[9];
        tap_setup(p, off, val);
        const float* src = bevs + (size_t)img*64*PP;
        float acc = cb[0];
#pragma unroll 2
        for (int c=0;c<64;c++){
            const float* sc = src + (size_t)c*PP;
            float v[9];
#pragma unroll
            for (int t=0;t<9;t++) v[t] = sc[off[t]];
            vmin = fminf(vmin, v[4]); vmax = fmaxf(vmax, v[4]);
#pragma unroll
            for (int t=0;t<9;t++)
                acc = fmaf(cw[c*9+t], val[t] ? v[t] : 0.0f, acc);
        }
        com[(size_t)img*PP + p] = fmaxf(acc, 0.0f);
    }
    if (n > 0){
#pragma unroll
        for (int s=32;s>0;s>>=1){
            vmin = fminf(vmin, __shfl_xor(vmin, s, 64));
            vmax = fmaxf(vmax, __shfl_xor(vmax, s, 64));
        }
        if ((threadIdx.x & 63) == 0){
            int im12 = (img/5)*4 + (n-1);
            atomicMin(&misc[im12], f2ord(vmin));
            atomicMax(&misc[12+im12], f2ord(vmax));
        }
    }
}

__global__ __launch_bounds__(256) void k_ent(const float* __restrict__ com,
        float* __restrict__ ent)
{
    int img = blockIdx.y;
    int p = blockIdx.x*256 + threadIdx.x;
    if (p >= PP) return;
    int off[9]; bool val[9];
    tap_setup(p, off, val);
    const float* s = com + (size_t)img*PP;
    float x = s[p];
    float v[9];
#pragma unroll
    for (int t=0;t<9;t++) v[t] = s[off[t]];
    float acc = 0.0f;
#pragma unroll
    for (int t=0;t<9;t++){
        float xv = val[t] ? v[t] : 0.0f;
        acc += 1.0f/(1.0f + expf(x - xv));
    }
    ent[(size_t)img*PP + p] = acc / 9.0f;
}

// big path: mask + per-block partial count (no hot atomic)
__global__ __launch_bounds__(256) void k_maskp(const float* __restrict__ ent,
        float* __restrict__ maskb, unsigned* __restrict__ partial)
{
    __shared__ unsigned cnt[4];
    int im12 = blockIdx.y; int bt = im12 >> 2; int n = (im12 & 3) + 1;
    int p = blockIdx.x*256 + threadIdx.x;
    int v = 0;
    if (p < PP){
        float en = ent[(size_t)(bt*5+n)*PP + p];
        float et = ent[(size_t)(bt*5)*PP + p];
        v = en > et;
        maskb[(size_t)im12*PP + p] = (float)v;
    }
    unsigned long long bal = __ballot(v);
    if ((threadIdx.x & 63) == 0) cnt[threadIdx.x>>6] = (unsigned)__popcll(bal);
    __syncthreads();
    if (threadIdx.x == 0)
        partial[blockIdx.y*GX + blockIdx.x] = cnt[0]+cnt[1]+cnt[2]+cnt[3];
}

// FALLBACK mask (atomic)
__global__ __launch_bounds__(256) void k_mask(const float* __restrict__ ent,
        float* __restrict__ maskb, unsigned* __restrict__ misc)
{
    int im12 = blockIdx.y; int bt = im12 >> 2; int n = (im12 & 3) + 1;
    int p = blockIdx.x*256 + threadIdx.x;
    int v = 0;
    if (p < PP){
        float en = ent[(size_t)(bt*5+n)*PP + p];
        float et = ent[(size_t)(bt*5)*PP + p];
        v = en > et;
        maskb[(size_t)im12*PP + p] = (float)v;
    }
    unsigned long long bal = __ballot(v);
    if ((threadIdx.x & 63) == 0) atomicAdd(&misc[24], (unsigned)__popcll(bal));
}

__global__ __launch_bounds__(256) void k_den(const float* __restrict__ maskb,
        float* __restrict__ denb)
{
    int im12 = blockIdx.y;
    int p = blockIdx.x*256 + threadIdx.x;
    if (p >= PP) return;
    int off[9]; bool val[9];
    tap_setup(p, off, val);
    const float* mrow = maskb + (size_t)im12*PP;
    float v[9];
#pragma unroll
    for (int t=0;t<9;t++) v[t] = mrow[off[t]];
    float s = 0.0f;
#pragma unroll
    for (int t=0;t<9;t++) s += val[t] ? v[t] : 0.0f;
    denb[(size_t)im12*PP + p] = s;
}

// big path: finalize iszero + bandwidth from partial counts (1 block, 256 thr)
__global__ __launch_bounds__(256) void k_finp(const unsigned* __restrict__ partial,
        unsigned* misc, float* bwout)
{
    __shared__ unsigned sh[4];
    unsigned s = 0;
    for (int i = threadIdx.x; i < NPART; i += 256) s += partial[i];
#pragma unroll
    for (int sft=32;sft>0;sft>>=1) s += (unsigned)__shfl_xor((int)s, sft, 64);
    if ((threadIdx.x & 63) == 0) sh[threadIdx.x>>6] = s;
    __syncthreads();
    int t = threadIdx.x;
    if (t < 12){
        float mn = ord2f(misc[t]);
        float mx = ord2f(misc[12+t]);
        ((int*)misc)[25+t] = (mn + mx == 0.0f) ? 1 : 0;
    }
    if (t == 12) bwout[0] = (float)(sh[0]+sh[1]+sh[2]+sh[3]) / 480000.0f;
}

// FALLBACK finalize
__global__ void k_fin(unsigned* misc, float* bwout){
    int t = threadIdx.x;
    if (t < 12){
        float mn = ord2f(misc[t]);
        float mx = ord2f(misc[12+t]);
        ((int*)misc)[25+t] = (mn + mx == 0.0f) ? 1 : 0;
    }
    if (t == 12) bwout[0] = (float)misc[24] / 480000.0f;
}

// ---------------------------------------------------------------------------
// k_xtg: Xtg[bt][chunk=8][PP][8] = bf16(tg), LDS transpose.
// grid (625, 3), block 256.
// ---------------------------------------------------------------------------
__global__ __launch_bounds__(256) void k_xtg(const float* __restrict__ bevs,
        short* __restrict__ Xtg)
{
    __shared__ short tile[64][72];     // [px_local][ch], rows 144B (16B-mult)
    int tid = threadIdx.x;
    int bt = blockIdx.y;
    int px0 = blockIdx.x*64;
    const float* tg = bevs + (size_t)bt*5*64*PP;
    int c = tid>>2, q = tid&3;
#pragma unroll
    for (int j=0;j<4;j++){
        int pxl = q*16 + j*4;
        f32x4 v = *(const f32x4*)&tg[(size_t)c*PP + px0 + pxl];
#pragma unroll
        for (int e=0;e<4;e++) tile[pxl+e][c] = f2bf(v[e]);
    }
    __syncthreads();
    int pxl = tid&63, qq = tid>>6;     // qq: 0..3 -> chunks 2qq, 2qq+1
    short* base = Xtg + (size_t)bt*PP*64;
    *(bf16x8*)&base[((size_t)(2*qq  )*PP + px0 + pxl)*8] = *(bf16x8*)&tile[pxl][qq*16];
    *(bf16x8*)&base[((size_t)(2*qq+1)*PP + px0 + pxl)*8] = *(bf16x8*)&tile[pxl][qq*16+8];
}

// ---------------------------------------------------------------------------
// k_xft v4 (edge loads scalarized): the f32x4 edge-window loads (v0/v2, of
// which only one element was used) are replaced by SCALAR loads at the
// clamped columns cl/cr. Bit-identical: interior cols load the same float;
// at image edges the differing taps are exactly the colok-masked ones
// (fmaf(0,.,acc) no-op). Cuts ~24 VGPR of dead register bytes -> allocator
// should land <=102 naturally (5-6 waves/SIMD). NOTE: do NOT add a min-waves
// launch_bounds (r15/r22: wholesale spill).
// Xft[im12][chunk=8][PP][8]. Thread: 4 consecutive px x 8 ch.
// grid (40, 12, 8), block 256.
// ---------------------------------------------------------------------------
__global__ __launch_bounds__(256) void k_xft(const float* __restrict__ bevs,
        const float* __restrict__ maskb,
        const unsigned* __restrict__ misc, short* __restrict__ Xft)
{
    int im12 = blockIdx.y; int bt = im12 >> 2; int n = (im12 & 3) + 1;
    int chunk = blockIdx.z;
    int chb = chunk*8;
    int idx = blockIdx.x*256 + threadIdx.x;
    if (idx >= PP/4) return;
    int p = idx*4;
    int row = p / WDIM, col0 = p - row*WDIM;
    int cl = max(col0-1, 0), cr = min(col0+4, WDIM-1);
    int rowc[3]; bool rowok[3];
#pragma unroll
    for (int r=0;r<3;r++){
        int rr = row + r - 1;
        rowok[r] = (rr>=0) && (rr<HDIM);
        rowc[r] = min(max(rr,0),HDIM-1) * WDIM;
    }
    bool colok[6];
#pragma unroll
    for (int k=0;k<6;k++){
        int cc = col0 + k - 1;
        colok[k] = (cc>=0) && (cc<WDIM);
    }
    const float* mrow = maskb + (size_t)im12*PP;
    float m6[3][6];
#pragma unroll
    for (int r=0;r<3;r++){
        f32x4 a1 = *(const f32x4*)&mrow[rowc[r] + col0];
        float mle = mrow[rowc[r] + cl];
        float mri = mrow[rowc[r] + cr];
        float mv[6] = {mle, a1[0], a1[1], a1[2], a1[3], mri};
#pragma unroll
        for (int k=0;k<6;k++)
            m6[r][k] = (rowok[r] && colok[k]) ? mv[k] : 0.0f;
    }
    // den inline: exact 0/1 sum, replaces k_den + denb read
    float rden[4];
#pragma unroll
    for (int j=0;j<4;j++){
        float d = 0.0f;
#pragma unroll
        for (int r=0;r<3;r++){
#pragma unroll
            for (int dk=0;dk<3;dk++) d += m6[r][j+dk];
        }
        rden[j] = 1.0f/(d + NEPS);
    }
    int iz = ((const int*)misc)[25+im12];
    const float* nbb = bevs + (size_t)(bt*5+n)*64*PP;

    short fv0[8], fv1[8], fv2[8], fv3[8];
#pragma unroll
    for (int ci=0;ci<8;ci++){
        int c = chb + ci;
        const float* sc = nbb + (size_t)c*PP;
        f32x4 vc[3]; float le[3], ri[3];
#pragma unroll
        for (int r=0;r<3;r++){
            vc[r] = *(const f32x4*)&sc[rowc[r] + col0];
            le[r] = sc[rowc[r] + cl];
            ri[r] = sc[rowc[r] + cr];
        }
        float num[4];
#pragma unroll
        for (int j=0;j<4;j++) num[j] = 0.0f;
#pragma unroll
        for (int r=0;r<3;r++){
            float vv[6] = {le[r], vc[r][0], vc[r][1], vc[r][2], vc[r][3], ri[r]};
#pragma unroll
            for (int j=0;j<4;j++){
#pragma unroll
                for (int dk=0;dk<3;dk++)
                    num[j] = fmaf(m6[r][j+dk], vv[j+dk], num[j]);
            }
        }
        short out4[4];
#pragma unroll
        for (int j=0;j<4;j++){
            float center = vc[1][j];
            float mc = m6[1][j+1];
            float xc = iz ? center : fmaf(mc, center, (1.0f-mc)*(num[j]*rden[j]));
            out4[j] = f2bf(xc);
        }
        fv0[ci]=out4[0]; fv1[ci]=out4[1]; fv2[ci]=out4[2]; fv3[ci]=out4[3];
    }
    short* xc0 = Xft + (size_t)im12*PP*64 + ((size_t)chunk*PP + p)*8;
    *(bf16x8*)&xc0[0]  = *(bf16x8*)&fv0[0];
    *(bf16x8*)&xc0[8]  = *(bf16x8*)&fv1[0];
    *(bf16x8*)&xc0[16] = *(bf16x8*)&fv2[0];
    *(bf16x8*)&xc0[24] = *(bf16x8*)&fv3[0];
}

// ---------------------------------------------------------------------------
// k_mlp: GEMM. W1 staged to LDS via linear bf16x8 copy (fragment-ordered);
// W2 fragments in registers. grid (157, 15), block 256.
// ---------------------------------------------------------------------------
__global__ __launch_bounds__(256) void k_mlp(const short* __restrict__ Xtg,
        const short* __restrict__ Xft, const short* __restrict__ wbf,
        const float* __restrict__ b1, const float* __restrict__ b2,
        const float* __restrict__ w3, const float* __restrict__ b3,
        const float* __restrict__ w4, const float* __restrict__ b4,
        float* __restrict__ logits)
{
    __shared__ __align__(16) short w1t[16384];      // fragment-ordered
    __shared__ __align__(16) short xt2[4*16*136];
    __shared__ __align__(16) float z2[4*16*33];
    __shared__ float b1l[128], b2l[32], b3l[8], w3l[8*33], w4l[8], b4l[1];

    int tid = threadIdx.x;
    int img = blockIdx.y, bt = img/5, n = img%5;

#pragma unroll
    for (int k=0;k<8;k++){
        int i = tid + k*256;
        *(bf16x8*)&w1t[i*8] = *(const bf16x8*)&wbf[i*8];
    }
    if (tid<256) w3l[(tid>>5)*33 + (tid&31)] = w3[tid];
    if (tid<128) b1l[tid]=b1[tid];
    if (tid<32)  b2l[tid]=b2[tid];
    if (tid<8)   b3l[tid]=b3[tid];
    if (tid<8)   w4l[tid]=w4[tid];
    if (tid==0)  b4l[0]=b4[0];

    int w = tid>>6, l = tid&63;
    int ln = l&15, kg = l>>4;

    bf16x8 w2f[2][4];
#pragma unroll
    for (int nt2=0;nt2<2;nt2++)
#pragma unroll
    for (int ks=0;ks<4;ks++)
        w2f[nt2][ks] = *(const bf16x8*)&wbf[16384 + ((nt2*4+ks)*64 + l)*8];

    __syncthreads();

    const short* xtgb = Xtg + (size_t)bt*PP*64;
    const short* xftb = (n>0) ? (Xft + (size_t)(bt*4+n-1)*PP*64) : xtgb;
    short* xt2w = &xt2[w*16*136];
    float* z2w  = &z2[w*16*33];
    int px_base = blockIdx.x*256 + w*64;

#pragma unroll 1
    for (int mt=0; mt<4; mt++){
        int prow = px_base + mt*16;
        int arow = prow + ln; if (arow > PP-1) arow = PP-1;
        bf16x8 af[4];
        af[0] = *(const bf16x8*)&xtgb[((size_t)kg*PP     + arow)*8];
        af[1] = *(const bf16x8*)&xtgb[((size_t)(kg+4)*PP + arow)*8];
        af[2] = *(const bf16x8*)&xftb[((size_t)kg*PP     + arow)*8];
        af[3] = *(const bf16x8*)&xftb[((size_t)(kg+4)*PP + arow)*8];

#pragma unroll
        for (int nt=0;nt<8;nt++){
            float bias = b1l[nt*16 + ln];
            f32x4 acc = {bias, bias, bias, bias};
#pragma unroll
            for (int ks=0;ks<4;ks++){
                bf16x8 bf = *(const bf16x8*)&w1t[((nt*4+ks)*64 + l)*8];
                acc = __builtin_amdgcn_mfma_f32_16x16x32_bf16(af[ks], bf, acc, 0, 0, 0);
            }
#pragma unroll
            for (int r=0;r<4;r++)
                xt2w[(kg*4+r)*136 + nt*16 + ln] = f2bf(fmaxf(acc[r], 0.0f));
        }

        bf16x8 a2[4];
#pragma unroll
        for (int ks=0;ks<4;ks++)
            a2[ks] = *(const bf16x8*)&xt2w[ln*136 + ks*32 + kg*8];
#pragma unroll
        for (int nt2=0;nt2<2;nt2++){
            float bias = b2l[nt2*16 + ln];
            f32x4 acc = {bias, bias, bias, bias};
#pragma unroll
            for (int ks=0;ks<4;ks++)
                acc = __builtin_amdgcn_mfma_f32_16x16x32_bf16(a2[ks], w2f[nt2][ks], acc, 0, 0, 0);
#pragma unroll
            for (int r=0;r<4;r++)
                z2w[(kg*4+r)*33 + nt2*16 + ln] = fmaxf(acc[r], 0.0f);
        }

        int k0 = kg*2, k1 = kg*2+1;
        float y0 = b3l[k0], y1 = b3l[k1];
#pragma unroll
        for (int j=0;j<32;j++){
            float v = z2w[ln*33 + j];
            y0 = fmaf(w3l[k0*33+j], v, y0);
            y1 = fmaf(w3l[k1*33+j], v, y1);
        }
        float part = w4l[k0]*fmaxf(y0,0.0f) + w4l[k1]*fmaxf(y1,0.0f);
        part += __shfl_xor(part, 16, 64);
        part += __shfl_xor(part, 32, 64);
        if (kg == 0 && prow + ln < PP)
            logits[(size_t)img*PP + prow + ln] = fmaxf(part + b4l[0], 0.0f);
    }
}

// ---------------------------------------------------------------------------
// k_fuse2: softmax + weighted sum (tg fp32 from bevs, warp bf16 from Xft chunks)
// grid (157, 3, 2)
// ---------------------------------------------------------------------------
__global__ __launch_bounds__(256) void k_fuse2(const float* __restrict__ bevs,
        const float* __restrict__ logits, const short* __restrict__ Xft,
        float* __restrict__ out)
{
    int bt = blockIdx.y;
    int cb = blockIdx.z*32;
    int chunk0 = cb>>3;
    int p = blockIdx.x*256 + threadIdx.x;
    if (p >= PP) return;
    float e[5], ssum = 0.0f;
#pragma unroll
    for (int nn=0;nn<5;nn++){ e[nn] = expf(logits[(size_t)(bt*5+nn)*PP + p]); ssum += e[nn]; }
    float rs = 1.0f/ssum;
    const float* tgb = bevs + (size_t)bt*5*64*PP;
    float acc[32];
    float w0 = e[0]*rs;
#pragma unroll
    for (int ci=0;ci<32;ci++) acc[ci] = w0*tgb[(size_t)(cb+ci)*PP + p];
#pragma unroll
    for (int k=0;k<4;k++){
        float wk = e[k+1]*rs;
        const short* Xim = Xft + (size_t)(bt*4+k)*PP*64;
#pragma unroll
        for (int c8=0;c8<4;c8++){
            bf16x8 v = *(const bf16x8*)&Xim[((size_t)(chunk0+c8)*PP + p)*8];
#pragma unroll
            for (int j=0;j<8;j++)
                acc[c8*8+j] = fmaf(wk, bf2f(v[j]), acc[c8*8+j]);
        }
    }
#pragma unroll
    for (int ci=0;ci<32;ci++)
        out[((size_t)bt*64 + cb+ci)*PP + p] = acc[ci];
}

// ---------------------------------------------------------------------------
// FALLBACK path (fused kernels) if ws too small
// ---------------------------------------------------------------------------
__global__ __launch_bounds__(256) void k_pwf(const float* __restrict__ bevs,
        const float* __restrict__ w1, const float* __restrict__ b1,
        const float* __restrict__ w2, const float* __restrict__ b2,
        const float* __restrict__ w3, const float* __restrict__ b3,
        const float* __restrict__ w4, const float* __restrict__ b4,
        const float* __restrict__ maskb, const float* __restrict__ denb,
        const unsigned* __restrict__ misc, float* __restrict__ logits)
{
    __shared__ __align__(16) short w1t[128*136];
    __shared__ __align__(16) short w2t[32*136];
    __shared__ __align__(16) short xt[64*136];
    __shared__ __align__(16) float z2[64*33];
    __shared__ float b1l[128], b2l[32], b3l[8], w3l[256], w4l[8], b4l[1];

    int tid = threadIdx.x;
    int img = blockIdx.y, bt = img/5, n = img%5;

    for (int i=tid;i<16384;i+=256) w1t[(i>>7)*136 + (i&127)] = f2bf(w1[i]);
    for (int i=tid;i<4096;i+=256)  w2t[(i>>7)*136 + (i&127)] = f2bf(w2[i]);
    if (tid<128) b1l[tid]=b1[tid];
    if (tid<32)  b2l[tid]=b2[tid];
    if (tid<8)   b3l[tid]=b3[tid];
    if (tid<256) w3l[tid]=w3[tid];
    if (tid<8)   w4l[tid]=w4[tid];
    if (tid==0)  b4l[0]=b4[0];

    int px = tid&63, q = tid>>6;
    int p = blockIdx.x*64 + px;
    const float* tg = bevs + (size_t)bt*5*64*PP;
    if (n == 0){
#pragma unroll
        for (int ci=0;ci<16;ci++){
            int c = q*16+ci;
            short v = f2bf(tg[(size_t)c*PP + p]);
            xt[px*136 + c] = v;
            xt[px*136 + 64 + c] = v;
        }
    } else {
        int im12 = bt*4 + (n-1);
        int off[9]; bool val[9];
        tap_setup(p, off, val);
        const float* mrow = maskb + (size_t)im12*PP;
        float m9[9];
#pragma unroll
        for (int t=0;t<9;t++) m9[t] = val[t] ? mrow[off[t]] : 0.0f;
        float rden = 1.0f/(denb[(size_t)im12*PP + p] + NEPS);
        int iz = ((const int*)misc)[25+im12];
        float mc = m9[4];
        const float* nbb = bevs + (size_t)(bt*5+n)*64*PP;
#pragma unroll
        for (int ci=0;ci<16;ci++){
            int c = q*16+ci;
            xt[px*136 + c] = f2bf(tg[(size_t)c*PP + p]);
            const float* sc = nbb + (size_t)c*PP;
            float num = 0.0f, center = 0.0f;
#pragma unroll
            for (int t=0;t<9;t++){
                if (val[t]){
                    float v = sc[off[t]];
                    num = fmaf(m9[t], v, num);
                    if (t==4) center = v;
                }
            }
            float xc = iz ? center : fmaf(mc, center, (1.0f-mc)*(num*rden));
            xt[px*136 + 64 + c] = f2bf(xc);
        }
    }
    __syncthreads();

    int w = tid>>6, l = tid&63;
    int ln = l&15, kg = l>>4;
    bf16x8 af[4];
#pragma unroll
    for (int ks=0;ks<4;ks++)
        af[ks] = *(const bf16x8*)&xt[(w*16+ln)*136 + ks*32 + kg*8];
#pragma unroll
    for (int nt=0;nt<8;nt++){
        float bias = b1l[nt*16 + ln];
        f32x4 acc = {bias, bias, bias, bias};
#pragma unroll
        for (int ks=0;ks<4;ks++){
            bf16x8 bf = *(const bf16x8*)&w1t[(nt*16+ln)*136 + ks*32 + kg*8];
            acc = __builtin_amdgcn_mfma_f32_16x16x32_bf16(af[ks], bf, acc, 0, 0, 0);
        }
#pragma unroll
        for (int r=0;r<4;r++){
            int pr = w*16 + kg*4 + r;
            xt[pr*136 + nt*16 + ln] = f2bf(fmaxf(acc[r], 0.0f));
        }
    }
    bf16x8 a2[4];
#pragma unroll
    for (int ks=0;ks<4;ks++)
        a2[ks] = *(const bf16x8*)&xt[(w*16+ln)*136 + ks*32 + kg*8];
#pragma unroll
    for (int nt2=0;nt2<2;nt2++){
        float bias = b2l[nt2*16 + ln];
        f32x4 acc = {bias, bias, bias, bias};
#pragma unroll
        for (int ks=0;ks<4;ks++){
            bf16x8 bf = *(const bf16x8*)&w2t[(nt2*16+ln)*136 + ks*32 + kg*8];
            acc = __builtin_amdgcn_mfma_f32_16x16x32_bf16(a2[ks], bf, acc, 0, 0, 0);
        }
#pragma unroll
        for (int r=0;r<4;r++){
            int pr = w*16 + kg*4 + r;
            z2[pr*33 + nt2*16 + ln] = fmaxf(acc[r], 0.0f);
        }
    }
    __syncthreads();
    if (tid < 64){
        float y3[8];
#pragma unroll
        for (int k=0;k<8;k++) y3[k] = b3l[k];
        for (int j=0;j<32;j++){
            float v = z2[tid*33 + j];
#pragma unroll
            for (int k=0;k<8;k++) y3[k] = fmaf(w3l[k*32+j], v, y3[k]);
        }
        float sres = b4l[0];
#pragma unroll
        for (int k=0;k<8;k++) sres = fmaf(w4l[k], fmaxf(y3[k], 0.0f), sres);
        logits[(size_t)img*PP + blockIdx.x*64 + tid] = fmaxf(sres, 0.0f);
    }
}

__global__ __launch_bounds__(256) void k_fuse_old(const float* __restrict__ bevs,
        const float* __restrict__ logits, const float* __restrict__ maskb,
        const float* __restrict__ denb, const unsigned* __restrict__ misc,
        float* __restrict__ out)
{
    int bt = blockIdx.y;
    int p = blockIdx.x*256 + threadIdx.x;
    if (p >= PP) return;
    int off[9]; bool val[9];
    tap_setup(p, off, val);
    float e[5], ssum = 0.0f;
#pragma unroll
    for (int nn=0;nn<5;nn++){ e[nn] = expf(logits[(size_t)(bt*5+nn)*PP + p]); ssum += e[nn]; }
    float wts[5];
#pragma unroll
    for (int nn=0;nn<5;nn++) wts[nn] = e[nn] / ssum;
    float m9[4][9]; float rden[4]; int iz[4];
#pragma unroll
    for (int k=0;k<4;k++){
        int im12 = bt*4 + k;
        const float* mrow = maskb + (size_t)im12*PP;
#pragma unroll
        for (int t=0;t<9;t++) m9[k][t] = val[t] ? mrow[off[t]] : 0.0f;
        rden[k] = 1.0f/(denb[(size_t)im12*PP + p] + NEPS);
        iz[k] = ((const int*)misc)[25+im12];
    }
    const float* base = bevs + (size_t)bt*5*64*PP;
    for (int c=0;c<64;c++){
        float tgc = base[(size_t)c*PP + p];
        float fused = wts[0]*tgc;
#pragma unroll
        for (int k=0;k<4;k++){
            const float* sc = base + (size_t)(k+1)*64*PP + (size_t)c*PP;
            float num = 0.0f, center = 0.0f;
#pragma unroll
            for (int t=0;t<9;t++){
                if (val[t]){
                    float v = sc[off[t]];
                    num = fmaf(m9[k][t], v, num);
                    if (t==4) center = v;
                }
            }
            float mc = m9[k][4];
            float xc = iz[k] ? center : fmaf(mc, center, (1.0f-mc)*(num*rden[k]));
            fused = fmaf(wts[k+1], xc, fused);
        }
        out[((size_t)bt*64 + c)*PP + p] = fused;
    }
}

extern "C" void kernel_launch(void* const* d_in, const int* in_sizes, int n_in,
                              void* d_out, int out_size, void* d_ws, size_t ws_size,
                              hipStream_t stream)
{
    const float* bevs = (const float*)d_in[0];
    const float* cw  = (const float*)d_in[1];
    const float* cb  = (const float*)d_in[2];
    const float* w1  = (const float*)d_in[3];
    const float* b1  = (const float*)d_in[4];
    const float* w2  = (const float*)d_in[5];
    const float* b2  = (const float*)d_in[6];
    const float* w3  = (const float*)d_in[7];
    const float* b3  = (const float*)d_in[8];
    const float* w4  = (const float*)d_in[9];
    const float* b4  = (const float*)d_in[10];
    float* out = (float*)d_out;
    float* ws = (float*)d_ws;

    float* com    = ws + OFF_COM;
    float* ent    = ws + OFF_ENT;
    float* maskb  = ws + OFF_MASK;
    float* denb   = ws + OFF_DEN;
    float* logits = ws + OFF_LOGITS;
    unsigned* misc = (unsigned*)(ws + OFF_MISC);
    short* Xtg    = (short*)(ws + OFF_XTG_F);
    short* Xft    = (short*)(ws + OFF_XFT_F);
    short* wbf    = (short*)(ws + OFF_WBF_F);
    unsigned* cntp = (unsigned*)(ws + OFF_CNT_F);
    float* z      = (float*)(ws + OFF_XFT_F);   // overlaps Xft; dead before Xft written

    dim3 blk(256,1,1);
    int gx = GX;
    bool big = ws_size >= WS_NEED;

    k_init<<<dim3(1),dim3(64),0,stream>>>(misc);
    if (big){
        k_wcvt<<<dim3(80),blk,0,stream>>>(w1,w2,wbf);
        k_csum<<<dim3((PP/4+255)/256,15),blk,0,stream>>>(bevs,cw,misc,z);
        k_cfin<<<dim3(gx,15),blk,0,stream>>>(z,cb,com);
        k_xtg <<<dim3(PP/64,3),blk,0,stream>>>(bevs,Xtg);
    } else {
        k_conv<<<dim3(gx,15),blk,0,stream>>>(bevs,cw,cb,com,misc);
    }
    k_ent <<<dim3(gx,15),blk,0,stream>>>(com,ent);
    if (big){
        k_maskp<<<dim3(gx,12),blk,0,stream>>>(ent,maskb,cntp);
        k_finp<<<dim3(1),blk,0,stream>>>(cntp, misc, out + (size_t)3*64*PP);
        k_xft  <<<dim3((PP/4+255)/256,12,8),blk,0,stream>>>(bevs,maskb,misc,Xft);
        k_mlp  <<<dim3(gx,15),blk,0,stream>>>(Xtg,Xft,wbf,b1,b2,w3,b3,w4,b4,logits);
        k_fuse2<<<dim3(gx,3,2),blk,0,stream>>>(bevs,logits,Xft,out);
    } else {
        k_mask<<<dim3(gx,12),blk,0,stream>>>(ent,maskb,misc);
        k_den <<<dim3(gx,12),blk,0,stream>>>(maskb,denb);
        k_fin <<<dim3(1),dim3(64),0,stream>>>(misc, out + (size_t)3*64*PP);
        k_pwf  <<<dim3(PP/64,15),blk,0,stream>>>(bevs,w1,b1,w2,b2,w3,b3,w4,b4,maskb,denb,misc,logits);
        k_fuse_old<<<dim3(gx,3),blk,0,stream>>>(bevs,logits,maskb,denb,misc,out);
    }
}